// Round 8
// baseline (288.353 us; speedup 1.0000x reference)
//
#include <hip/hip_runtime.h>
#include <math.h>

#define NLEVEL 16
#define TSIZE 16384
#define ESTRIDE 65536   // encode: 64 slices x 1024 threads

using half4 = __attribute__((ext_vector_type(4))) _Float16;
using f32x4 = __attribute__((ext_vector_type(4))) float;
using f32x2 = __attribute__((ext_vector_type(2))) float;
using u32x2 = __attribute__((ext_vector_type(2))) unsigned;
typedef __fp16 hv2 __attribute__((ext_vector_type(2)));

struct NsParam { int n[NLEVEL]; unsigned densemask; };

union Frag { half4 v; int i[2]; };
union Hu { unsigned u; hv2 h; };

// A-fragment for mfma_f32_16x16x16f16 of W^T (W row-major [K][N] fp32):
// lane (pt=lane&15, q=lane>>4) holds A[m=out][k=k0+4q+j], j=0..3.
__device__ __forceinline__ Frag load_wfrag(const float* __restrict__ W, int ldn,
                                           int k0, int q, int out,
                                           int kmax, int omax) {
    Frag f;
    #pragma unroll
    for (int j = 0; j < 4; ++j) {
        int k = k0 + 4 * q + j;
        float v = (k < kmax && out < omax) ? W[k * ldn + out] : 0.0f;
        f.v[j] = (_Float16)v;
    }
    return f;
}

__device__ __forceinline__ f32x4 mfma16(const Frag& a, const Frag& b, f32x4 c) {
    return __builtin_amdgcn_mfma_f32_16x16x16f16(a.v, b.v, c, 0, 0, 0);
}

// relu + cvt: C-tile f32x4 -> B-fragment half4 (layouts match for K=16!)
__device__ __forceinline__ Frag actpack(f32x4 a) {
    Frag f;
    #pragma unroll
    for (int j = 0; j < 4; ++j) f.v[j] = (_Float16)fmaxf(a[j], 0.0f);
    return f;
}

__device__ __forceinline__ float sigmoidf(float x) {
    return 1.0f / (1.0f + expf(-x));
}

// q-select among 4 values (q = lane>>4)
__device__ __forceinline__ int qsel(int q, int a, int b, int c, int d) {
    return (q & 2) ? ((q & 1) ? d : c) : ((q & 1) ? b : a);
}

// packed f32x2 -> fp16x2 (RTZ; staging the LDS table copy)
__device__ __forceinline__ unsigned pkrtz(float a, float b) {
    union { hv2 h; unsigned u; } r;
    r.h = __builtin_amdgcn_cvt_pkrtz(a, b);
    return r.u;
}

__device__ __forceinline__ hv2 splath(float w) {
    Hu r; r.u = pkrtz(w, w); return r.h;
}

// packed-fp16 lerp: a + w*(b-a)
__device__ __forceinline__ hv2 hlerp(hv2 a, hv2 b, hv2 w) {
    return (hv2)((b - a) * w + a);
}

// ============================================================================
// Phase A: hash-grid encode, level-persistent blocks.
// Round-8 deltas: (1) 1024 blocks (16 levels x 64 slices) -> CU slots get a
// second generation of blocks, refilling behind early-finishing dense-level
// blocks (r7 occupancy 57% was zero-refill load imbalance). (2) nontemporal
// ws stores: 128MB ws stream was evicting the 16x-reread x (48MB) from L3
// (r7 FETCH 230MB). (3) byte-offset Gray-code hash: pre-shift components by
// 2 (shift distributes over XOR and mod-2^32 mul -> bit-exact), derive the
// 8 corner hashes with 7 XORs, masked value IS the ds_read byte address.
// ============================================================================

// Compute one point's 8 table byte-offsets and ISSUE the 8 LDS gathers.
__device__ __forceinline__ void gather_issue(
    const unsigned* __restrict__ tab,
    float cxp, float cyp, float czp,
    float fn, int np1b, int np1sqb, int dense,
    unsigned fe[8], float& w0, float& w1, float& w2)
{
    float xl0 = cxp * fn, xl1 = cyp * fn, xl2 = czp * fn;
    float f0 = floorf(xl0), f1 = floorf(xl1), f2 = floorf(xl2);
    int i0 = (int)f0, i1 = (int)f1, i2 = (int)f2;
    w0 = xl0 - f0; w1 = xl1 - f1; w2 = xl2 - f2;
    const char* tb = (const char*)tab;
    if (dense) {   // block-uniform branch (levels 0,1 only)
        int b000 = i0 * np1sqb + i1 * np1b + (i2 << 2);
        #pragma unroll
        for (int c = 0; c < 8; ++c) {
            int o0 = (c >> 2) & 1, o1 = (c >> 1) & 1, o2 = c & 1;
            int off = b000 + (o0 ? np1sqb : 0) + (o1 ? np1b : 0) + (o2 << 2);
            fe[c] = *(const unsigned*)(tb + off);
        }
    } else {
        unsigned HX = (unsigned)i0 << 2;
        unsigned HY = (unsigned)i1 * (2654435761u << 2);
        unsigned HZ = (unsigned)i2 * (805459861u << 2);
        unsigned A  = HX ^ HY ^ HZ;
        unsigned DX = HX ^ (HX + 4u);
        unsigned DY = HY ^ (HY + (2654435761u << 2));
        unsigned DZ = HZ ^ (HZ + (805459861u << 2));
        const unsigned mask = (TSIZE - 1) << 2;
        unsigned b00 = A,        b10 = A ^ DX;
        unsigned b01 = b00 ^ DY, b11 = b10 ^ DY;
        fe[0] = *(const unsigned*)(tb + (b00 & mask));
        fe[1] = *(const unsigned*)(tb + ((b00 ^ DZ) & mask));
        fe[2] = *(const unsigned*)(tb + (b01 & mask));
        fe[3] = *(const unsigned*)(tb + ((b01 ^ DZ) & mask));
        fe[4] = *(const unsigned*)(tb + (b10 & mask));
        fe[5] = *(const unsigned*)(tb + ((b10 ^ DZ) & mask));
        fe[6] = *(const unsigned*)(tb + (b11 & mask));
        fe[7] = *(const unsigned*)(tb + ((b11 ^ DZ) & mask));
    }
}

// fp16 trilinear tree-lerp over the 8 gathered corners -> fp16x2 feature pair
__device__ __forceinline__ unsigned interp_tree(
    const unsigned fe[8], float w0, float w1, float w2)
{
    hv2 W0 = splath(w0), W1 = splath(w1), W2 = splath(w2);
    Hu a, b;
    a.u = fe[0]; b.u = fe[1]; hv2 g00 = hlerp(a.h, b.h, W2);
    a.u = fe[2]; b.u = fe[3]; hv2 g01 = hlerp(a.h, b.h, W2);
    a.u = fe[4]; b.u = fe[5]; hv2 g10 = hlerp(a.h, b.h, W2);
    a.u = fe[6]; b.u = fe[7]; hv2 g11 = hlerp(a.h, b.h, W2);
    hv2 gy0 = hlerp(g00, g01, W1);
    hv2 gy1 = hlerp(g10, g11, W1);
    Hu r; r.h = hlerp(gy0, gy1, W0);
    return r.u;
}

// load+clamp 4 chunk coords (indices clamped so overrun prefetch is safe)
__device__ __forceinline__ void loadc4(
    const float* __restrict__ x, int g0, int chunk, int B,
    float cx[4], float cy[4], float cz[4])
{
    #pragma unroll
    for (int p = 0; p < 4; ++p) {
        int idx = g0 + (chunk * 4 + p) * ESTRIDE;
        idx = (idx < B) ? idx : (B - 1);
        const float* xp = x + (size_t)idx * 6;
        f32x2 a = *(const f32x2*)xp;
        float pz = xp[2];
        cx[p] = fminf(fmaxf((a.x + 5.0f) / 10.0f, 0.0f), 0.999999f);
        cy[p] = fminf(fmaxf((a.y + 5.0f) / 10.0f, 0.0f), 0.999999f);
        cz[p] = fminf(fmaxf((pz  + 5.0f) / 10.0f, 0.0f), 0.999999f);
    }
}

// gather/interp pipeline over one 4-point chunk (1-ahead LDS pipeline)
__device__ __forceinline__ void enc_chunk(
    const unsigned* __restrict__ tab, unsigned* __restrict__ wplane,
    int g0, int chunk, int B,
    const float cx[4], const float cy[4], const float cz[4],
    float fn, int np1b, int np1sqb, int dense)
{
    unsigned fe[2][8];
    float w0s[2], w1s[2], w2s[2];
    gather_issue(tab, cx[0], cy[0], cz[0], fn, np1b, np1sqb, dense,
                 fe[0], w0s[0], w1s[0], w2s[0]);
    #pragma unroll
    for (int p = 0; p < 4; ++p) {
        if (p + 1 < 4)
            gather_issue(tab, cx[p + 1], cy[p + 1], cz[p + 1],
                         fn, np1b, np1sqb, dense,
                         fe[(p + 1) & 1], w0s[(p + 1) & 1],
                         w1s[(p + 1) & 1], w2s[(p + 1) & 1]);
        unsigned pk = interp_tree(fe[p & 1], w0s[p & 1], w1s[p & 1], w2s[p & 1]);
        int idx = g0 + (chunk * 4 + p) * ESTRIDE;
        if (idx < B) __builtin_nontemporal_store(pk, wplane + idx);
    }
}

__global__ __launch_bounds__(1024, 8) void nerf_encode(
    const float* __restrict__ x,
    const float* __restrict__ embed,
    unsigned* __restrict__ ws, int B, NsParam ns)
{
    __shared__ unsigned tab[TSIZE];   // fp16x2 entries, 64 KB -> 2 blocks/CU
    const int tid = threadIdx.x;
    const int l = blockIdx.x & 15;        // level (interleaved for refill mix)
    const int slice = blockIdx.x >> 4;    // 0..63

    // stage this level's fp16 table ONCE
    {
        const f32x4* src = (const f32x4*)(embed + (size_t)l * (TSIZE * 2));
        #pragma unroll
        for (int j = 0; j < 8; ++j) {
            f32x4 v = src[tid + 1024 * j];
            u32x2 pk;
            pk.x = pkrtz(v.x, v.y);
            pk.y = pkrtz(v.z, v.w);
            *(u32x2*)(tab + 2 * (tid + 1024 * j)) = pk;
        }
    }
    __syncthreads();

    const int n = ns.n[l];
    const float fn = (float)n;
    const int np1b = (n + 1) << 2, np1sqb = (n + 1) * (n + 1) << 2;
    const int dense = (ns.densemask >> l) & 1;
    unsigned* __restrict__ wplane = ws + (size_t)l * B;

    const int g0 = slice * 1024 + tid;    // 0..65535
    const int nIter = (B + ESTRIDE - 1) / ESTRIDE;   // points per thread (32)
    const int NC = (nIter + 3) >> 2;                 // 4-pt chunks (8)

    // chunked coord prefetch: chunk c+1's 8 VMEM loads are in flight for the
    // whole ~600cy of chunk c's gathers+interp -> L3 latency hidden.
    float cxA[4], cyA[4], czA[4], cxB[4], cyB[4], czB[4];
    loadc4(x, g0, 0, B, cxA, cyA, czA);
    for (int c = 0; c < NC; c += 2) {
        loadc4(x, g0, c + 1, B, cxB, cyB, czB);
        enc_chunk(tab, wplane, g0, c, B, cxA, cyA, czA, fn, np1b, np1sqb, dense);
        loadc4(x, g0, c + 2, B, cxA, cyA, czA);
        if (c + 1 < NC)
            enc_chunk(tab, wplane, g0, c + 1, B, cxB, cyB, czB,
                      fn, np1b, np1sqb, dense);
    }
}

// ============================================================================
// Phase B: MFMA MLP, 32 points per wave-iteration (two independent chains).
// Unchanged from round 7 (control -- should now surface in top-5 for
// counters): cW0/cW1 + biases in LDS, launch_bounds(256,4), 1-deep prefetch
// as the only per-iteration VMEM.
// ============================================================================
struct Pre { Frag f0[2], f1[2]; float vx[2], vy[2], vz[2]; };

__device__ __forceinline__ void prefetch_tile(
    const unsigned* __restrict__ ws, int B, int q,
    const float* __restrict__ x, int tile32, int pt, Pre& P)
{
    const unsigned* pl0 = ws + (size_t)(2 * q) * B;
    const unsigned* pl1 = ws + (size_t)(2 * q + 1) * B;
    const unsigned* pl2 = ws + (size_t)(8 + 2 * q) * B;
    const unsigned* pl3 = ws + (size_t)(9 + 2 * q) * B;
    #pragma unroll
    for (int g = 0; g < 2; ++g) {
        int ptg = tile32 * 32 + g * 16 + pt;
        P.f0[g].i[0] = (int)__builtin_nontemporal_load(pl0 + ptg);
        P.f0[g].i[1] = (int)__builtin_nontemporal_load(pl1 + ptg);
        P.f1[g].i[0] = (int)__builtin_nontemporal_load(pl2 + ptg);
        P.f1[g].i[1] = (int)__builtin_nontemporal_load(pl3 + ptg);
        const float* xp = x + (size_t)ptg * 6;
        P.vx[g] = xp[3];
        f32x2 v45 = *(const f32x2*)(xp + 4);
        P.vy[g] = v45.x; P.vz[g] = v45.y;
    }
}

__global__ __launch_bounds__(256, 4) void nerf_mlp(
    const float* __restrict__ x,
    const unsigned* __restrict__ ws,
    const float* __restrict__ dW0, const float* __restrict__ db0,
    const float* __restrict__ dW1, const float* __restrict__ db1,
    const float* __restrict__ cW0, const float* __restrict__ cb0,
    const float* __restrict__ cW1, const float* __restrict__ cb1,
    const float* __restrict__ cW2, const float* __restrict__ cb2,
    float* __restrict__ out, int B)
{
    const int lane = threadIdx.x & 63;
    const int pt = lane & 15;
    const int q  = lane >> 4;
    const int tid = threadIdx.x;
    const int wavesPerBlock = blockDim.x >> 6;
    const int waveId = blockIdx.x * wavesPerBlock + (threadIdx.x >> 6);
    const int waveStride = gridDim.x * wavesPerBlock;
    const int numT = B >> 5;   // 32-pt tiles

    // LDS-resident: cW0 (8 frags x 64 lanes), cW1 (16 x 64), biases
    __shared__ Frag wldsC0[8][64];    // 4 KB
    __shared__ Frag wldsC1[16][64];   // 8 KB
    __shared__ f32x4 blds[14][4];     // 896 B
    for (int e = tid; e < 8 * 64; e += 256) {
        int f = e >> 6, ln = e & 63;
        wldsC0[f][ln] = load_wfrag(cW0, 64, 16 * (f & 1), ln >> 4,
                                   16 * (f >> 1) + (ln & 15), 19, 64);
    }
    for (int e = tid; e < 16 * 64; e += 256) {
        int f = e >> 6, ln = e & 63;
        wldsC1[f][ln] = load_wfrag(cW1, 64, 16 * (f & 3), ln >> 4,
                                   16 * (f >> 2) + (ln & 15), 64, 64);
    }
    if (tid < 56) {
        int f = tid >> 2, qq = tid & 3;
        f32x4 v;
        if (f < 4)       v = *(const f32x4*)(db0 + 16 * f + 4 * qq);
        else if (f == 4) v = *(const f32x4*)(db1 + 4 * qq);
        else if (f < 9)  v = *(const f32x4*)(cb0 + 16 * (f - 5) + 4 * qq);
        else if (f < 13) v = *(const f32x4*)(cb1 + 16 * (f - 9) + 4 * qq);
        else {
            v[0] = (qq == 0) ? cb2[0] : 0.0f;
            v[1] = (qq == 0) ? cb2[1] : 0.0f;
            v[2] = (qq == 0) ? cb2[2] : 0.0f;
            v[3] = 0.0f;
        }
        blds[f][qq] = v;
    }

    // VGPR-resident weights: dW0 (8), dW1 (4), cW2 (4) frags = 32 VGPRs
    Frag wdW0[4][2], wdW1[4], wcW2[4];
    #pragma unroll
    for (int t = 0; t < 4; ++t)
        #pragma unroll
        for (int c = 0; c < 2; ++c)
            wdW0[t][c] = load_wfrag(dW0, 64, 16 * c, q, 16 * t + pt, 32, 64);
    #pragma unroll
    for (int c = 0; c < 4; ++c)
        wdW1[c] = load_wfrag(dW1, 16, 16 * c, q, pt, 64, 16);
    #pragma unroll
    for (int c = 0; c < 4; ++c)
        wcW2[c] = load_wfrag(cW2, 3, 16 * c, q, pt, 64, 3);

    __syncthreads();

    int tile = waveId;
    if (tile >= numT) return;

    Pre P;
    prefetch_tile(ws, B, q, x, tile, pt, P);

    for (;;) {
        int next = tile + waveStride;
        bool hasNext = next < numT;

        // consume prefetched registers (waits on loads issued 1 iter ago)
        Frag bf0[2] = { P.f0[0], P.f0[1] };
        Frag bf1[2] = { P.f1[0], P.f1[1] };
        float vx[2] = { P.vx[0], P.vx[1] };
        float vy[2] = { P.vy[0], P.vy[1] };
        float vz[2] = { P.vz[0], P.vz[1] };
        const int ptbase = tile * 32;

        if (hasNext) prefetch_tile(ws, B, q, x, next, pt, P);

        // fresh opaque indices each iteration: stops LICM hoisting the
        // loop-invariant LDS reads back into permanently-live VGPRs.
        int wl = lane, wq = q;
        asm("" : "+v"(wl));
        asm("" : "+v"(wq));

        __builtin_amdgcn_s_setprio(1);

        // ---- L0: h64 = dW0^T @ feats (4 out-tiles, K=32) x 2 chains ----
        f32x4 acc[2][4];
        #pragma unroll
        for (int t = 0; t < 4; ++t) {
            f32x4 b = blds[t][wq];
            #pragma unroll
            for (int g = 0; g < 2; ++g) {
                f32x4 a = b;
                a = mfma16(wdW0[t][0], bf0[g], a);
                a = mfma16(wdW0[t][1], bf1[g], a);
                acc[g][t] = a;
            }
        }
        Frag bh[2][4];
        #pragma unroll
        for (int c = 0; c < 4; ++c)
            #pragma unroll
            for (int g = 0; g < 2; ++g) bh[g][c] = actpack(acc[g][c]);

        // ---- L1: h16 = dW1^T @ relu(h64) (1 tile, K=64) ----
        f32x4 bl1 = blds[4][wq];
        f32x4 h[2] = { bl1, bl1 };
        #pragma unroll
        for (int c = 0; c < 4; ++c)
            #pragma unroll
            for (int g = 0; g < 2; ++g) h[g] = mfma16(wdW1[c], bh[g][c], h[g]);

        float dens[2];
        Frag bcin0[2], bcin1[2];
        #pragma unroll
        for (int g = 0; g < 2; ++g) {
            dens[g] = sigmoidf(h[g][0]);        // row 0 lives at q==0, reg 0
            float a0v = (q == 0) ? dens[g] : fmaxf(h[g][0], 0.0f);
            bcin0[g].v[0] = (_Float16)a0v;
            bcin0[g].v[1] = (_Float16)fmaxf(h[g][1], 0.0f);
            bcin0[g].v[2] = (_Float16)fmaxf(h[g][2], 0.0f);
            bcin0[g].v[3] = (_Float16)fmaxf(h[g][3], 0.0f);
            // k=16+4q+j: q==0 holds k16..19 = (vx,vy,vz,0) of its own point
            bcin1[g].v[0] = (_Float16)((q == 0) ? vx[g] : 0.0f);
            bcin1[g].v[1] = (_Float16)((q == 0) ? vy[g] : 0.0f);
            bcin1[g].v[2] = (_Float16)((q == 0) ? vz[g] : 0.0f);
            bcin1[g].v[3] = (_Float16)0.0f;
        }

        // ---- L2: c1 = cW0^T @ cin (4 out-tiles, K=19 padded to 32) ----
        #pragma unroll
        for (int t = 0; t < 4; ++t) {
            f32x4 b = blds[5 + t][wq];
            Frag w0f = wldsC0[2 * t + 0][wl];
            Frag w1f = wldsC0[2 * t + 1][wl];
            #pragma unroll
            for (int g = 0; g < 2; ++g) {
                f32x4 a = b;
                a = mfma16(w0f, bcin0[g], a);
                a = mfma16(w1f, bcin1[g], a);
                acc[g][t] = a;
            }
        }
        Frag bc[2][4];
        #pragma unroll
        for (int c = 0; c < 4; ++c)
            #pragma unroll
            for (int g = 0; g < 2; ++g) bc[g][c] = actpack(acc[g][c]);

        // ---- L3: c2 = cW1^T @ relu(c1) (4 out-tiles, K=64) ----
        #pragma unroll
        for (int t = 0; t < 4; ++t) {
            f32x4 b = blds[9 + t][wq];
            #pragma unroll
            for (int g = 0; g < 2; ++g) acc[g][t] = b;
            #pragma unroll
            for (int c = 0; c < 4; ++c) {
                Frag wf = wldsC1[4 * t + c][wl];
                #pragma unroll
                for (int g = 0; g < 2; ++g)
                    acc[g][t] = mfma16(wf, bc[g][c], acc[g][t]);
            }
        }
        Frag bd[2][4];
        #pragma unroll
        for (int c = 0; c < 4; ++c)
            #pragma unroll
            for (int g = 0; g < 2; ++g) bd[g][c] = actpack(acc[g][c]);

        // ---- L4: col = cW2^T @ relu(c2) (rows 0..2, K=64) ----
        f32x4 bl4 = blds[13][wq];
        f32x4 fo[2] = { bl4, bl4 };
        #pragma unroll
        for (int c = 0; c < 4; ++c)
            #pragma unroll
            for (int g = 0; g < 2; ++g) fo[g] = mfma16(wcW2[c], bd[g][c], fo[g]);

        __builtin_amdgcn_s_setprio(0);

        if (q == 0) {
            #pragma unroll
            for (int g = 0; g < 2; ++g) {
                f32x4 o;
                o[0] = dens[g];
                o[1] = sigmoidf(fo[g][0]);
                o[2] = sigmoidf(fo[g][1]);
                o[3] = sigmoidf(fo[g][2]);
                __builtin_nontemporal_store(o,
                    (f32x4*)(out + (size_t)(ptbase + g * 16 + pt) * 4));
            }
        }

        if (!hasNext) break;
        tile = next;
    }
}

// ============================================================================
// Fallback: fused single kernel if ws_size is insufficient (unchanged).
// ============================================================================
__device__ __forceinline__ void opaque(const float*& p) {
    asm("" : "+v"(p));
}

__device__ __forceinline__ void enc_issue(
    float px, float py, float pz,
    const float fn_[4], const float* const eb_[4],
    const int np1_[4], const int np1sq_[4], const bool dense_[4],
    f32x2 fe[4][8], float w_[4][3])
{
    float cx = fminf(fmaxf((px + 5.0f) / 10.0f, 0.0f), 0.999999f);
    float cy = fminf(fmaxf((py + 5.0f) / 10.0f, 0.0f), 0.999999f);
    float cz = fminf(fmaxf((pz + 5.0f) / 10.0f, 0.0f), 0.999999f);

    #pragma unroll
    for (int d = 0; d < 4; ++d) {
        float fn = fn_[d];
        float xl0 = cx * fn, xl1 = cy * fn, xl2 = cz * fn;
        float f0 = floorf(xl0), f1 = floorf(xl1), f2 = floorf(xl2);
        int i0 = (int)f0, i1 = (int)f1, i2 = (int)f2;
        w_[d][0] = xl0 - f0; w_[d][1] = xl1 - f1; w_[d][2] = xl2 - f2;

        unsigned hx0 = (unsigned)i0, hx1 = hx0 + 1u;
        unsigned hy0 = (unsigned)i1 * 2654435761u, hy1 = hy0 + 2654435761u;
        unsigned hz0 = (unsigned)i2 * 805459861u,  hz1 = hz0 + 805459861u;
        int dx0 = 0, dx1 = 0, dy0 = 0, dy1 = 0;
        if (d < 2) {
            dx0 = i0 * np1sq_[d]; dx1 = dx0 + np1sq_[d];
            dy0 = i1 * np1_[d];   dy1 = dy0 + np1_[d];
        }
        #pragma unroll
        for (int c = 0; c < 8; ++c) {
            int o0 = (c >> 2) & 1, o1 = (c >> 1) & 1, o2 = c & 1;
            unsigned h = (o0 ? hx1 : hx0) ^ (o1 ? hy1 : hy0) ^ (o2 ? hz1 : hz0);
            int ind = (int)(h & (TSIZE - 1));
            if (d < 2) {
                int di = (o0 ? dx1 : dx0) + (o1 ? dy1 : dy0) + i2 + o2;
                ind = dense_[d] ? di : ind;
            }
            fe[d][c] = *(const f32x2*)(eb_[d] + (size_t)ind * 2);
        }
    }
}

__global__ __launch_bounds__(256) void nerf_fused(
    const float* __restrict__ x,
    const float* __restrict__ embed,
    const float* __restrict__ dW0, const float* __restrict__ db0,
    const float* __restrict__ dW1, const float* __restrict__ db1,
    const float* __restrict__ cW0, const float* __restrict__ cb0,
    const float* __restrict__ cW1, const float* __restrict__ cb1,
    const float* __restrict__ cW2, const float* __restrict__ cb2,
    float* __restrict__ out, int B, NsParam ns)
{
    const int lane = threadIdx.x & 63;
    const int pt = lane & 15;
    const int q  = lane >> 4;
    const int wavesPerBlock = blockDim.x >> 6;
    const int waveId = blockIdx.x * wavesPerBlock + (threadIdx.x >> 6);
    const int waveStride = gridDim.x * wavesPerBlock;
    const int numTiles = B >> 4;

    Frag wdW0[4][2], wdW1[4], wcW0[4][2], wcW1[4][4], wcW2[4];
    #pragma unroll
    for (int t = 0; t < 4; ++t)
        #pragma unroll
        for (int c = 0; c < 2; ++c)
            wdW0[t][c] = load_wfrag(dW0, 64, 16 * c, q, 16 * t + pt, 32, 64);
    #pragma unroll
    for (int c = 0; c < 4; ++c)
        wdW1[c] = load_wfrag(dW1, 16, 16 * c, q, pt, 64, 16);
    #pragma unroll
    for (int t = 0; t < 4; ++t)
        #pragma unroll
        for (int c = 0; c < 2; ++c)
            wcW0[t][c] = load_wfrag(cW0, 64, 16 * c, q, 16 * t + pt, 19, 64);
    #pragma unroll
    for (int t = 0; t < 4; ++t)
        #pragma unroll
        for (int c = 0; c < 4; ++c)
            wcW1[t][c] = load_wfrag(cW1, 64, 16 * c, q, 16 * t + pt, 64, 64);
    #pragma unroll
    for (int c = 0; c < 4; ++c)
        wcW2[c] = load_wfrag(cW2, 3, 16 * c, q, pt, 64, 3);

    float fn_[4];
    const float* eb_[4];
    int np1_[4], np1sq_[4];
    bool dense_[4];
    #pragma unroll
    for (int d = 0; d < 4; ++d) {
        int base = (d < 2) ? (d) : (8 + (d - 2));
        int lvl = base + 2 * q;
        int n = qsel(q, ns.n[base], ns.n[base + 2], ns.n[base + 4], ns.n[base + 6]);
        fn_[d] = (float)n;
        np1_[d] = n + 1;
        np1sq_[d] = (n + 1) * (n + 1);
        dense_[d] = (ns.densemask >> lvl) & 1u;
        eb_[d] = embed + (size_t)lvl * (TSIZE * 2);
    }

    for (int tile = waveId; tile < numTiles; tile += waveStride) {
        const int ptg = tile * 16 + pt;
        const float* xp = x + (size_t)ptg * 6;
        f32x2 x01 = *(const f32x2*)(xp);
        f32x2 x23 = *(const f32x2*)(xp + 2);
        f32x2 x45 = *(const f32x2*)(xp + 4);
        float vx = x23.y, vy = x45.x, vz = x45.y;

        f32x2 fe[4][8];
        float w_[4][3];
        enc_issue(x01.x, x01.y, x23.x, fn_, eb_, np1_, np1sq_, dense_, fe, w_);

        Frag bf0, bf1;
        #pragma unroll
        for (int d = 0; d < 4; ++d) {
            float w0 = w_[d][0], w1 = w_[d][1], w2 = w_[d][2];
            float u0 = 1.0f - w0, u1 = 1.0f - w1, u2 = 1.0f - w2;
            float wxy[4] = { u0 * u1, u0 * w1, w0 * u1, w0 * w1 };
            float a0 = 0.0f, a1 = 0.0f;
            #pragma unroll
            for (int c = 0; c < 8; ++c) {
                float ww = wxy[c >> 1] * ((c & 1) ? w2 : u2);
                a0 = fmaf(fe[d][c].x, ww, a0);
                a1 = fmaf(fe[d][c].y, ww, a1);
            }
            if (d == 0)      { bf0.v[0] = (_Float16)a0; bf0.v[1] = (_Float16)a1; }
            else if (d == 1) { bf0.v[2] = (_Float16)a0; bf0.v[3] = (_Float16)a1; }
            else if (d == 2) { bf1.v[0] = (_Float16)a0; bf1.v[1] = (_Float16)a1; }
            else             { bf1.v[2] = (_Float16)a0; bf1.v[3] = (_Float16)a1; }
        }

        const float* db0o = db0; const float* db1o = db1;
        const float* cb0o = cb0; const float* cb1o = cb1;
        const float* cb2o = cb2;
        opaque(db0o); opaque(db1o); opaque(cb0o); opaque(cb1o); opaque(cb2o);

        f32x4 acc[4];
        #pragma unroll
        for (int t = 0; t < 4; ++t) {
            acc[t] = *(const f32x4*)(db0o + 16 * t + 4 * q);
            acc[t] = mfma16(wdW0[t][0], bf0, acc[t]);
            acc[t] = mfma16(wdW0[t][1], bf1, acc[t]);
        }
        Frag bh[4];
        #pragma unroll
        for (int c = 0; c < 4; ++c) bh[c] = actpack(acc[c]);

        f32x4 h = *(const f32x4*)(db1o + 4 * q);
        #pragma unroll
        for (int c = 0; c < 4; ++c) h = mfma16(wdW1[c], bh[c], h);

        float dens = sigmoidf(h[0]);
        Frag bcin0, bcin1;
        {
            float a0v = (q == 0) ? dens : fmaxf(h[0], 0.0f);
            bcin0.v[0] = (_Float16)a0v;
            bcin0.v[1] = (_Float16)fmaxf(h[1], 0.0f);
            bcin0.v[2] = (_Float16)fmaxf(h[2], 0.0f);
            bcin0.v[3] = (_Float16)fmaxf(h[3], 0.0f);
            bcin1.v[0] = (_Float16)((q == 0) ? vx : 0.0f);
            bcin1.v[1] = (_Float16)((q == 0) ? vy : 0.0f);
            bcin1.v[2] = (_Float16)((q == 0) ? vz : 0.0f);
            bcin1.v[3] = (_Float16)0.0f;
        }

        #pragma unroll
        for (int t = 0; t < 4; ++t) {
            acc[t] = *(const f32x4*)(cb0o + 16 * t + 4 * q);
            acc[t] = mfma16(wcW0[t][0], bcin0, acc[t]);
            acc[t] = mfma16(wcW0[t][1], bcin1, acc[t]);
        }
        Frag bc[4];
        #pragma unroll
        for (int c = 0; c < 4; ++c) bc[c] = actpack(acc[c]);

        #pragma unroll
        for (int t = 0; t < 4; ++t) {
            acc[t] = *(const f32x4*)(cb1o + 16 * t + 4 * q);
            #pragma unroll
            for (int c = 0; c < 4; ++c) acc[t] = mfma16(wcW1[t][c], bc[c], acc[t]);
        }
        Frag bd[4];
        #pragma unroll
        for (int c = 0; c < 4; ++c) bd[c] = actpack(acc[c]);

        float b0 = cb2o[0], b1 = cb2o[1], b2 = cb2o[2];
        f32x4 fo;
        fo[0] = (q == 0) ? b0 : 0.0f;
        fo[1] = (q == 0) ? b1 : 0.0f;
        fo[2] = (q == 0) ? b2 : 0.0f;
        fo[3] = 0.0f;
        #pragma unroll
        for (int c = 0; c < 4; ++c) fo = mfma16(wcW2[c], bd[c], fo);

        if (q == 0) {
            f32x4 o;
            o[0] = dens;
            o[1] = sigmoidf(fo[0]);
            o[2] = sigmoidf(fo[1]);
            o[3] = sigmoidf(fo[2]);
            *(f32x4*)(out + (size_t)ptg * 4) = o;
        }
    }
}

extern "C" void kernel_launch(void* const* d_in, const int* in_sizes, int n_in,
                              void* d_out, int out_size, void* d_ws, size_t ws_size,
                              hipStream_t stream) {
    const float* x    = (const float*)d_in[0];
    const float* embed= (const float*)d_in[1];
    const float* dW0  = (const float*)d_in[2];
    const float* db0  = (const float*)d_in[3];
    const float* dW1  = (const float*)d_in[4];
    const float* db1  = (const float*)d_in[5];
    const float* cW0  = (const float*)d_in[6];
    const float* cb0  = (const float*)d_in[7];
    const float* cW1  = (const float*)d_in[8];
    const float* cb1  = (const float*)d_in[9];
    const float* cW2  = (const float*)d_in[10];
    const float* cb2  = (const float*)d_in[11];
    float* out = (float*)d_out;

    int B = in_sizes[0] / 6;

    // Replicate numpy's NS computation bit-for-bit (same libm on this host).
    NsParam ns;
    double g = exp((log(512.0) - log(16.0)) / 15.0);
    ns.densemask = 0;
    for (int i = 0; i < NLEVEL; ++i) {
        ns.n[i] = (int)(16.0 * pow(g, (double)i));
        long long np1 = ns.n[i] + 1;
        if (np1 * np1 * np1 <= TSIZE) ns.densemask |= (1u << i);
    }

    size_t wsNeed = (size_t)NLEVEL * (size_t)B * 4;   // fp16x2 per (level,point)
    if (ws_size >= wsNeed && d_ws != nullptr && (B & 31) == 0 && B >= 32) {
        unsigned* ws = (unsigned*)d_ws;
        nerf_encode<<<1024, 1024, 0, stream>>>(x, embed, ws, B, ns);
        nerf_mlp<<<2048, 256, 0, stream>>>(x, ws,
            dW0, db0, dW1, db1, cW0, cb0, cW1, cb1, cW2, cb2, out, B);
    } else {
        nerf_fused<<<2048, 256, 0, stream>>>(x, embed,
            dW0, db0, dW1, db1, cW0, cb0, cW1, cb1, cW2, cb2, out, B, ns);
    }
}

// Round 9
// 254.950 us; speedup vs baseline: 1.1310x; 1.1310x over previous
//
#include <hip/hip_runtime.h>
#include <math.h>

#define NLEVEL 16
#define TSIZE 16384
#define ESTRIDE 65536   // encode: 64 slices x 1024 threads

using half4 = __attribute__((ext_vector_type(4))) _Float16;
using f32x4 = __attribute__((ext_vector_type(4))) float;
using f32x2 = __attribute__((ext_vector_type(2))) float;
using u32x2 = __attribute__((ext_vector_type(2))) unsigned;
typedef __fp16 hv2 __attribute__((ext_vector_type(2)));

struct NsParam { int n[NLEVEL]; unsigned densemask; };

union Frag { half4 v; int i[2]; };
union Hu { unsigned u; hv2 h; };

// A-fragment for mfma_f32_16x16x16f16 of W^T (W row-major [K][N] fp32):
// lane (pt=lane&15, q=lane>>4) holds A[m=out][k=k0+4q+j], j=0..3.
__device__ __forceinline__ Frag load_wfrag(const float* __restrict__ W, int ldn,
                                           int k0, int q, int out,
                                           int kmax, int omax) {
    Frag f;
    #pragma unroll
    for (int j = 0; j < 4; ++j) {
        int k = k0 + 4 * q + j;
        float v = (k < kmax && out < omax) ? W[k * ldn + out] : 0.0f;
        f.v[j] = (_Float16)v;
    }
    return f;
}

__device__ __forceinline__ f32x4 mfma16(const Frag& a, const Frag& b, f32x4 c) {
    return __builtin_amdgcn_mfma_f32_16x16x16f16(a.v, b.v, c, 0, 0, 0);
}

// relu + cvt: C-tile f32x4 -> B-fragment half4 (layouts match for K=16!)
__device__ __forceinline__ Frag actpack(f32x4 a) {
    Frag f;
    #pragma unroll
    for (int j = 0; j < 4; ++j) f.v[j] = (_Float16)fmaxf(a[j], 0.0f);
    return f;
}

__device__ __forceinline__ float sigmoidf(float x) {
    return 1.0f / (1.0f + expf(-x));
}

// q-select among 4 values (q = lane>>4)
__device__ __forceinline__ int qsel(int q, int a, int b, int c, int d) {
    return (q & 2) ? ((q & 1) ? d : c) : ((q & 1) ? b : a);
}

// packed f32x2 -> fp16x2 (RTZ; staging the LDS table copy)
__device__ __forceinline__ unsigned pkrtz(float a, float b) {
    union { hv2 h; unsigned u; } r;
    r.h = __builtin_amdgcn_cvt_pkrtz(a, b);
    return r.u;
}

__device__ __forceinline__ hv2 splath(float w) {
    Hu r; r.u = pkrtz(w, w); return r.h;
}

// packed-fp16 lerp: a + w*(b-a)
__device__ __forceinline__ hv2 hlerp(hv2 a, hv2 b, hv2 w) {
    return (hv2)((b - a) * w + a);
}

// ============================================================================
// Phase 0 (round-9): coord prep. Reads x ONCE, writes clamped coords as
// u16x3 packed in 8B/point (16MB). Encode's 16x re-read then touches a
// 16MB L3-resident array instead of the 48MB x (r8 FETCH 220MB = x misses),
// and the clamp VALU chain is done once instead of 16x.
// Quantization: qx = trunc(cx*65536), xl = qx*(fn/65536); err <= 2^-16 unit
// coords -> feature err ~3e-6 (trilinear is C0) << 0.0039 absmax budget.
// ============================================================================
__global__ __launch_bounds__(256) void nerf_prep(
    const float* __restrict__ x, u32x2* __restrict__ qc, int B)
{
    int i = blockIdx.x * blockDim.x + threadIdx.x;
    const int stride = gridDim.x * blockDim.x;
    for (; i < B; i += stride) {
        const float* xp = x + (size_t)i * 6;
        f32x2 a = *(const f32x2*)xp;
        float pz = xp[2];
        float cx = fminf(fmaxf((a.x + 5.0f) / 10.0f, 0.0f), 0.999999f);
        float cy = fminf(fmaxf((a.y + 5.0f) / 10.0f, 0.0f), 0.999999f);
        float cz = fminf(fmaxf((pz  + 5.0f) / 10.0f, 0.0f), 0.999999f);
        unsigned qx = (unsigned)(cx * 65536.0f);   // <= 65535
        unsigned qy = (unsigned)(cy * 65536.0f);
        unsigned qz = (unsigned)(cz * 65536.0f);
        u32x2 o; o.x = qx | (qy << 16); o.y = qz;
        qc[i] = o;
    }
}

// ============================================================================
// Phase A: hash-grid encode, level-persistent blocks (r7/r8 structure:
// fp16 table staged once per block, byte-offset Gray-code hash, 1024 blocks
// for refill, nt feature stores). Round-9 delta: coords come from the
// 8B/point qcoord array (template<QC>); raw-x variant kept as fallback.
// ============================================================================

// Compute one point's 8 table byte-offsets and ISSUE the 8 LDS gathers.
// cx,cy,cz are raw (quantized or clamped) coords; scale = fn or fn/65536.
__device__ __forceinline__ void gather_issue(
    const unsigned* __restrict__ tab,
    float cxp, float cyp, float czp,
    float scale, int np1b, int np1sqb, int dense,
    unsigned fe[8], float& w0, float& w1, float& w2)
{
    float xl0 = cxp * scale, xl1 = cyp * scale, xl2 = czp * scale;
    float f0 = floorf(xl0), f1 = floorf(xl1), f2 = floorf(xl2);
    int i0 = (int)f0, i1 = (int)f1, i2 = (int)f2;
    w0 = xl0 - f0; w1 = xl1 - f1; w2 = xl2 - f2;
    const char* tb = (const char*)tab;
    if (dense) {   // block-uniform branch (levels 0,1 only)
        int b000 = i0 * np1sqb + i1 * np1b + (i2 << 2);
        #pragma unroll
        for (int c = 0; c < 8; ++c) {
            int o0 = (c >> 2) & 1, o1 = (c >> 1) & 1, o2 = c & 1;
            int off = b000 + (o0 ? np1sqb : 0) + (o1 ? np1b : 0) + (o2 << 2);
            fe[c] = *(const unsigned*)(tb + off);
        }
    } else {
        unsigned HX = (unsigned)i0 << 2;
        unsigned HY = (unsigned)i1 * (2654435761u << 2);
        unsigned HZ = (unsigned)i2 * (805459861u << 2);
        unsigned A  = HX ^ HY ^ HZ;
        unsigned DX = HX ^ (HX + 4u);
        unsigned DY = HY ^ (HY + (2654435761u << 2));
        unsigned DZ = HZ ^ (HZ + (805459861u << 2));
        const unsigned mask = (TSIZE - 1) << 2;
        unsigned b00 = A,        b10 = A ^ DX;
        unsigned b01 = b00 ^ DY, b11 = b10 ^ DY;
        fe[0] = *(const unsigned*)(tb + (b00 & mask));
        fe[1] = *(const unsigned*)(tb + ((b00 ^ DZ) & mask));
        fe[2] = *(const unsigned*)(tb + (b01 & mask));
        fe[3] = *(const unsigned*)(tb + ((b01 ^ DZ) & mask));
        fe[4] = *(const unsigned*)(tb + (b10 & mask));
        fe[5] = *(const unsigned*)(tb + ((b10 ^ DZ) & mask));
        fe[6] = *(const unsigned*)(tb + (b11 & mask));
        fe[7] = *(const unsigned*)(tb + ((b11 ^ DZ) & mask));
    }
}

// fp16 trilinear tree-lerp over the 8 gathered corners -> fp16x2 feature pair
__device__ __forceinline__ unsigned interp_tree(
    const unsigned fe[8], float w0, float w1, float w2)
{
    hv2 W0 = splath(w0), W1 = splath(w1), W2 = splath(w2);
    Hu a, b;
    a.u = fe[0]; b.u = fe[1]; hv2 g00 = hlerp(a.h, b.h, W2);
    a.u = fe[2]; b.u = fe[3]; hv2 g01 = hlerp(a.h, b.h, W2);
    a.u = fe[4]; b.u = fe[5]; hv2 g10 = hlerp(a.h, b.h, W2);
    a.u = fe[6]; b.u = fe[7]; hv2 g11 = hlerp(a.h, b.h, W2);
    hv2 gy0 = hlerp(g00, g01, W1);
    hv2 gy1 = hlerp(g10, g11, W1);
    Hu r; r.h = hlerp(gy0, gy1, W0);
    return r.u;
}

// load 4 chunk coords (indices clamped so overrun prefetch is safe)
template <bool QC>
__device__ __forceinline__ void loadc4(
    const float* __restrict__ x, const unsigned* __restrict__ qc,
    int g0, int chunk, int B, float cx[4], float cy[4], float cz[4])
{
    #pragma unroll
    for (int p = 0; p < 4; ++p) {
        int idx = g0 + (chunk * 4 + p) * ESTRIDE;
        idx = (idx < B) ? idx : (B - 1);
        if (QC) {
            u32x2 qq = *((const u32x2*)qc + idx);
            cx[p] = (float)(qq.x & 0xFFFFu);
            cy[p] = (float)(qq.x >> 16);
            cz[p] = (float)qq.y;
        } else {
            const float* xp = x + (size_t)idx * 6;
            f32x2 a = *(const f32x2*)xp;
            float pz = xp[2];
            cx[p] = fminf(fmaxf((a.x + 5.0f) / 10.0f, 0.0f), 0.999999f);
            cy[p] = fminf(fmaxf((a.y + 5.0f) / 10.0f, 0.0f), 0.999999f);
            cz[p] = fminf(fmaxf((pz  + 5.0f) / 10.0f, 0.0f), 0.999999f);
        }
    }
}

// gather/interp pipeline over one 4-point chunk (1-ahead LDS pipeline)
__device__ __forceinline__ void enc_chunk(
    const unsigned* __restrict__ tab, unsigned* __restrict__ wplane,
    int g0, int chunk, int B,
    const float cx[4], const float cy[4], const float cz[4],
    float scale, int np1b, int np1sqb, int dense)
{
    unsigned fe[2][8];
    float w0s[2], w1s[2], w2s[2];
    gather_issue(tab, cx[0], cy[0], cz[0], scale, np1b, np1sqb, dense,
                 fe[0], w0s[0], w1s[0], w2s[0]);
    #pragma unroll
    for (int p = 0; p < 4; ++p) {
        if (p + 1 < 4)
            gather_issue(tab, cx[p + 1], cy[p + 1], cz[p + 1],
                         scale, np1b, np1sqb, dense,
                         fe[(p + 1) & 1], w0s[(p + 1) & 1],
                         w1s[(p + 1) & 1], w2s[(p + 1) & 1]);
        unsigned pk = interp_tree(fe[p & 1], w0s[p & 1], w1s[p & 1], w2s[p & 1]);
        int idx = g0 + (chunk * 4 + p) * ESTRIDE;
        if (idx < B) __builtin_nontemporal_store(pk, wplane + idx);
    }
}

template <bool QC>
__global__ __launch_bounds__(1024, 8) void nerf_encode(
    const float* __restrict__ x, const unsigned* __restrict__ qc,
    const float* __restrict__ embed,
    unsigned* __restrict__ ws, int B, NsParam ns)
{
    __shared__ unsigned tab[TSIZE];   // fp16x2 entries, 64 KB -> 2 blocks/CU
    const int tid = threadIdx.x;
    const int l = blockIdx.x & 15;        // level (interleaved for refill mix)
    const int slice = blockIdx.x >> 4;    // 0..63

    // stage this level's fp16 table ONCE
    {
        const f32x4* src = (const f32x4*)(embed + (size_t)l * (TSIZE * 2));
        #pragma unroll
        for (int j = 0; j < 8; ++j) {
            f32x4 v = src[tid + 1024 * j];
            u32x2 pk;
            pk.x = pkrtz(v.x, v.y);
            pk.y = pkrtz(v.z, v.w);
            *(u32x2*)(tab + 2 * (tid + 1024 * j)) = pk;
        }
    }
    __syncthreads();

    const int n = ns.n[l];
    const float scale = QC ? (float)n * (1.0f / 65536.0f) : (float)n;
    const int np1b = (n + 1) << 2, np1sqb = (n + 1) * (n + 1) << 2;
    const int dense = (ns.densemask >> l) & 1;
    unsigned* __restrict__ wplane = ws + (size_t)l * B;

    const int g0 = slice * 1024 + tid;    // 0..65535
    const int nIter = (B + ESTRIDE - 1) / ESTRIDE;   // points per thread (32)
    const int NC = (nIter + 3) >> 2;                 // 4-pt chunks (8)

    // chunked coord prefetch: chunk c+1's loads are in flight for the whole
    // ~600cy of chunk c's gathers+interp -> L2/L3 latency hidden.
    float cxA[4], cyA[4], czA[4], cxB[4], cyB[4], czB[4];
    loadc4<QC>(x, qc, g0, 0, B, cxA, cyA, czA);
    for (int c = 0; c < NC; c += 2) {
        loadc4<QC>(x, qc, g0, c + 1, B, cxB, cyB, czB);
        enc_chunk(tab, wplane, g0, c, B, cxA, cyA, czA,
                  scale, np1b, np1sqb, dense);
        loadc4<QC>(x, qc, g0, c + 2, B, cxA, cyA, czA);
        if (c + 1 < NC)
            enc_chunk(tab, wplane, g0, c + 1, B, cxB, cyB, czB,
                      scale, np1b, np1sqb, dense);
    }
}

// ============================================================================
// Phase B: MFMA MLP, 32 points per wave-iteration (two independent chains).
// Unchanged from round 7/8 (control): cW0/cW1 + biases in LDS,
// launch_bounds(256,4), 1-deep prefetch as the only per-iteration VMEM.
// ============================================================================
struct Pre { Frag f0[2], f1[2]; float vx[2], vy[2], vz[2]; };

__device__ __forceinline__ void prefetch_tile(
    const unsigned* __restrict__ ws, int B, int q,
    const float* __restrict__ x, int tile32, int pt, Pre& P)
{
    const unsigned* pl0 = ws + (size_t)(2 * q) * B;
    const unsigned* pl1 = ws + (size_t)(2 * q + 1) * B;
    const unsigned* pl2 = ws + (size_t)(8 + 2 * q) * B;
    const unsigned* pl3 = ws + (size_t)(9 + 2 * q) * B;
    #pragma unroll
    for (int g = 0; g < 2; ++g) {
        int ptg = tile32 * 32 + g * 16 + pt;
        P.f0[g].i[0] = (int)__builtin_nontemporal_load(pl0 + ptg);
        P.f0[g].i[1] = (int)__builtin_nontemporal_load(pl1 + ptg);
        P.f1[g].i[0] = (int)__builtin_nontemporal_load(pl2 + ptg);
        P.f1[g].i[1] = (int)__builtin_nontemporal_load(pl3 + ptg);
        const float* xp = x + (size_t)ptg * 6;
        P.vx[g] = xp[3];
        f32x2 v45 = *(const f32x2*)(xp + 4);
        P.vy[g] = v45.x; P.vz[g] = v45.y;
    }
}

__global__ __launch_bounds__(256, 4) void nerf_mlp(
    const float* __restrict__ x,
    const unsigned* __restrict__ ws,
    const float* __restrict__ dW0, const float* __restrict__ db0,
    const float* __restrict__ dW1, const float* __restrict__ db1,
    const float* __restrict__ cW0, const float* __restrict__ cb0,
    const float* __restrict__ cW1, const float* __restrict__ cb1,
    const float* __restrict__ cW2, const float* __restrict__ cb2,
    float* __restrict__ out, int B)
{
    const int lane = threadIdx.x & 63;
    const int pt = lane & 15;
    const int q  = lane >> 4;
    const int tid = threadIdx.x;
    const int wavesPerBlock = blockDim.x >> 6;
    const int waveId = blockIdx.x * wavesPerBlock + (threadIdx.x >> 6);
    const int waveStride = gridDim.x * wavesPerBlock;
    const int numT = B >> 5;   // 32-pt tiles

    // LDS-resident: cW0 (8 frags x 64 lanes), cW1 (16 x 64), biases
    __shared__ Frag wldsC0[8][64];    // 4 KB
    __shared__ Frag wldsC1[16][64];   // 8 KB
    __shared__ f32x4 blds[14][4];     // 896 B
    for (int e = tid; e < 8 * 64; e += 256) {
        int f = e >> 6, ln = e & 63;
        wldsC0[f][ln] = load_wfrag(cW0, 64, 16 * (f & 1), ln >> 4,
                                   16 * (f >> 1) + (ln & 15), 19, 64);
    }
    for (int e = tid; e < 16 * 64; e += 256) {
        int f = e >> 6, ln = e & 63;
        wldsC1[f][ln] = load_wfrag(cW1, 64, 16 * (f & 3), ln >> 4,
                                   16 * (f >> 2) + (ln & 15), 64, 64);
    }
    if (tid < 56) {
        int f = tid >> 2, qq = tid & 3;
        f32x4 v;
        if (f < 4)       v = *(const f32x4*)(db0 + 16 * f + 4 * qq);
        else if (f == 4) v = *(const f32x4*)(db1 + 4 * qq);
        else if (f < 9)  v = *(const f32x4*)(cb0 + 16 * (f - 5) + 4 * qq);
        else if (f < 13) v = *(const f32x4*)(cb1 + 16 * (f - 9) + 4 * qq);
        else {
            v[0] = (qq == 0) ? cb2[0] : 0.0f;
            v[1] = (qq == 0) ? cb2[1] : 0.0f;
            v[2] = (qq == 0) ? cb2[2] : 0.0f;
            v[3] = 0.0f;
        }
        blds[f][qq] = v;
    }

    // VGPR-resident weights: dW0 (8), dW1 (4), cW2 (4) frags = 32 VGPRs
    Frag wdW0[4][2], wdW1[4], wcW2[4];
    #pragma unroll
    for (int t = 0; t < 4; ++t)
        #pragma unroll
        for (int c = 0; c < 2; ++c)
            wdW0[t][c] = load_wfrag(dW0, 64, 16 * c, q, 16 * t + pt, 32, 64);
    #pragma unroll
    for (int c = 0; c < 4; ++c)
        wdW1[c] = load_wfrag(dW1, 16, 16 * c, q, pt, 64, 16);
    #pragma unroll
    for (int c = 0; c < 4; ++c)
        wcW2[c] = load_wfrag(cW2, 3, 16 * c, q, pt, 64, 3);

    __syncthreads();

    int tile = waveId;
    if (tile >= numT) return;

    Pre P;
    prefetch_tile(ws, B, q, x, tile, pt, P);

    for (;;) {
        int next = tile + waveStride;
        bool hasNext = next < numT;

        // consume prefetched registers (waits on loads issued 1 iter ago)
        Frag bf0[2] = { P.f0[0], P.f0[1] };
        Frag bf1[2] = { P.f1[0], P.f1[1] };
        float vx[2] = { P.vx[0], P.vx[1] };
        float vy[2] = { P.vy[0], P.vy[1] };
        float vz[2] = { P.vz[0], P.vz[1] };
        const int ptbase = tile * 32;

        if (hasNext) prefetch_tile(ws, B, q, x, next, pt, P);

        // fresh opaque indices each iteration: stops LICM hoisting the
        // loop-invariant LDS reads back into permanently-live VGPRs.
        int wl = lane, wq = q;
        asm("" : "+v"(wl));
        asm("" : "+v"(wq));

        __builtin_amdgcn_s_setprio(1);

        // ---- L0: h64 = dW0^T @ feats (4 out-tiles, K=32) x 2 chains ----
        f32x4 acc[2][4];
        #pragma unroll
        for (int t = 0; t < 4; ++t) {
            f32x4 b = blds[t][wq];
            #pragma unroll
            for (int g = 0; g < 2; ++g) {
                f32x4 a = b;
                a = mfma16(wdW0[t][0], bf0[g], a);
                a = mfma16(wdW0[t][1], bf1[g], a);
                acc[g][t] = a;
            }
        }
        Frag bh[2][4];
        #pragma unroll
        for (int c = 0; c < 4; ++c)
            #pragma unroll
            for (int g = 0; g < 2; ++g) bh[g][c] = actpack(acc[g][c]);

        // ---- L1: h16 = dW1^T @ relu(h64) (1 tile, K=64) ----
        f32x4 bl1 = blds[4][wq];
        f32x4 h[2] = { bl1, bl1 };
        #pragma unroll
        for (int c = 0; c < 4; ++c)
            #pragma unroll
            for (int g = 0; g < 2; ++g) h[g] = mfma16(wdW1[c], bh[g][c], h[g]);

        float dens[2];
        Frag bcin0[2], bcin1[2];
        #pragma unroll
        for (int g = 0; g < 2; ++g) {
            dens[g] = sigmoidf(h[g][0]);        // row 0 lives at q==0, reg 0
            float a0v = (q == 0) ? dens[g] : fmaxf(h[g][0], 0.0f);
            bcin0[g].v[0] = (_Float16)a0v;
            bcin0[g].v[1] = (_Float16)fmaxf(h[g][1], 0.0f);
            bcin0[g].v[2] = (_Float16)fmaxf(h[g][2], 0.0f);
            bcin0[g].v[3] = (_Float16)fmaxf(h[g][3], 0.0f);
            // k=16+4q+j: q==0 holds k16..19 = (vx,vy,vz,0) of its own point
            bcin1[g].v[0] = (_Float16)((q == 0) ? vx[g] : 0.0f);
            bcin1[g].v[1] = (_Float16)((q == 0) ? vy[g] : 0.0f);
            bcin1[g].v[2] = (_Float16)((q == 0) ? vz[g] : 0.0f);
            bcin1[g].v[3] = (_Float16)0.0f;
        }

        // ---- L2: c1 = cW0^T @ cin (4 out-tiles, K=19 padded to 32) ----
        #pragma unroll
        for (int t = 0; t < 4; ++t) {
            f32x4 b = blds[5 + t][wq];
            Frag w0f = wldsC0[2 * t + 0][wl];
            Frag w1f = wldsC0[2 * t + 1][wl];
            #pragma unroll
            for (int g = 0; g < 2; ++g) {
                f32x4 a = b;
                a = mfma16(w0f, bcin0[g], a);
                a = mfma16(w1f, bcin1[g], a);
                acc[g][t] = a;
            }
        }
        Frag bc[2][4];
        #pragma unroll
        for (int c = 0; c < 4; ++c)
            #pragma unroll
            for (int g = 0; g < 2; ++g) bc[g][c] = actpack(acc[g][c]);

        // ---- L3: c2 = cW1^T @ relu(c1) (4 out-tiles, K=64) ----
        #pragma unroll
        for (int t = 0; t < 4; ++t) {
            f32x4 b = blds[9 + t][wq];
            #pragma unroll
            for (int g = 0; g < 2; ++g) acc[g][t] = b;
            #pragma unroll
            for (int c = 0; c < 4; ++c) {
                Frag wf = wldsC1[4 * t + c][wl];
                #pragma unroll
                for (int g = 0; g < 2; ++g)
                    acc[g][t] = mfma16(wf, bc[g][c], acc[g][t]);
            }
        }
        Frag bd[2][4];
        #pragma unroll
        for (int c = 0; c < 4; ++c)
            #pragma unroll
            for (int g = 0; g < 2; ++g) bd[g][c] = actpack(acc[g][c]);

        // ---- L4: col = cW2^T @ relu(c2) (rows 0..2, K=64) ----
        f32x4 bl4 = blds[13][wq];
        f32x4 fo[2] = { bl4, bl4 };
        #pragma unroll
        for (int c = 0; c < 4; ++c)
            #pragma unroll
            for (int g = 0; g < 2; ++g) fo[g] = mfma16(wcW2[c], bd[g][c], fo[g]);

        __builtin_amdgcn_s_setprio(0);

        if (q == 0) {
            #pragma unroll
            for (int g = 0; g < 2; ++g) {
                f32x4 o;
                o[0] = dens[g];
                o[1] = sigmoidf(fo[g][0]);
                o[2] = sigmoidf(fo[g][1]);
                o[3] = sigmoidf(fo[g][2]);
                __builtin_nontemporal_store(o,
                    (f32x4*)(out + (size_t)(ptbase + g * 16 + pt) * 4));
            }
        }

        if (!hasNext) break;
        tile = next;
    }
}

// ============================================================================
// Fallback: fused single kernel if ws_size is insufficient (unchanged).
// ============================================================================
__device__ __forceinline__ void opaque(const float*& p) {
    asm("" : "+v"(p));
}

__device__ __forceinline__ void enc_issue(
    float px, float py, float pz,
    const float fn_[4], const float* const eb_[4],
    const int np1_[4], const int np1sq_[4], const bool dense_[4],
    f32x2 fe[4][8], float w_[4][3])
{
    float cx = fminf(fmaxf((px + 5.0f) / 10.0f, 0.0f), 0.999999f);
    float cy = fminf(fmaxf((py + 5.0f) / 10.0f, 0.0f), 0.999999f);
    float cz = fminf(fmaxf((pz + 5.0f) / 10.0f, 0.0f), 0.999999f);

    #pragma unroll
    for (int d = 0; d < 4; ++d) {
        float fn = fn_[d];
        float xl0 = cx * fn, xl1 = cy * fn, xl2 = cz * fn;
        float f0 = floorf(xl0), f1 = floorf(xl1), f2 = floorf(xl2);
        int i0 = (int)f0, i1 = (int)f1, i2 = (int)f2;
        w_[d][0] = xl0 - f0; w_[d][1] = xl1 - f1; w_[d][2] = xl2 - f2;

        unsigned hx0 = (unsigned)i0, hx1 = hx0 + 1u;
        unsigned hy0 = (unsigned)i1 * 2654435761u, hy1 = hy0 + 2654435761u;
        unsigned hz0 = (unsigned)i2 * 805459861u,  hz1 = hz0 + 805459861u;
        int dx0 = 0, dx1 = 0, dy0 = 0, dy1 = 0;
        if (d < 2) {
            dx0 = i0 * np1sq_[d]; dx1 = dx0 + np1sq_[d];
            dy0 = i1 * np1_[d];   dy1 = dy0 + np1_[d];
        }
        #pragma unroll
        for (int c = 0; c < 8; ++c) {
            int o0 = (c >> 2) & 1, o1 = (c >> 1) & 1, o2 = c & 1;
            unsigned h = (o0 ? hx1 : hx0) ^ (o1 ? hy1 : hy0) ^ (o2 ? hz1 : hz0);
            int ind = (int)(h & (TSIZE - 1));
            if (d < 2) {
                int di = (o0 ? dx1 : dx0) + (o1 ? dy1 : dy0) + i2 + o2;
                ind = dense_[d] ? di : ind;
            }
            fe[d][c] = *(const f32x2*)(eb_[d] + (size_t)ind * 2);
        }
    }
}

__global__ __launch_bounds__(256) void nerf_fused(
    const float* __restrict__ x,
    const float* __restrict__ embed,
    const float* __restrict__ dW0, const float* __restrict__ db0,
    const float* __restrict__ dW1, const float* __restrict__ db1,
    const float* __restrict__ cW0, const float* __restrict__ cb0,
    const float* __restrict__ cW1, const float* __restrict__ cb1,
    const float* __restrict__ cW2, const float* __restrict__ cb2,
    float* __restrict__ out, int B, NsParam ns)
{
    const int lane = threadIdx.x & 63;
    const int pt = lane & 15;
    const int q  = lane >> 4;
    const int wavesPerBlock = blockDim.x >> 6;
    const int waveId = blockIdx.x * wavesPerBlock + (threadIdx.x >> 6);
    const int waveStride = gridDim.x * wavesPerBlock;
    const int numTiles = B >> 4;

    Frag wdW0[4][2], wdW1[4], wcW0[4][2], wcW1[4][4], wcW2[4];
    #pragma unroll
    for (int t = 0; t < 4; ++t)
        #pragma unroll
        for (int c = 0; c < 2; ++c)
            wdW0[t][c] = load_wfrag(dW0, 64, 16 * c, q, 16 * t + pt, 32, 64);
    #pragma unroll
    for (int c = 0; c < 4; ++c)
        wdW1[c] = load_wfrag(dW1, 16, 16 * c, q, pt, 64, 16);
    #pragma unroll
    for (int t = 0; t < 4; ++t)
        #pragma unroll
        for (int c = 0; c < 2; ++c)
            wcW0[t][c] = load_wfrag(cW0, 64, 16 * c, q, 16 * t + pt, 19, 64);
    #pragma unroll
    for (int t = 0; t < 4; ++t)
        #pragma unroll
        for (int c = 0; c < 4; ++c)
            wcW1[t][c] = load_wfrag(cW1, 64, 16 * c, q, 16 * t + pt, 64, 64);
    #pragma unroll
    for (int c = 0; c < 4; ++c)
        wcW2[c] = load_wfrag(cW2, 3, 16 * c, q, pt, 64, 3);

    float fn_[4];
    const float* eb_[4];
    int np1_[4], np1sq_[4];
    bool dense_[4];
    #pragma unroll
    for (int d = 0; d < 4; ++d) {
        int base = (d < 2) ? (d) : (8 + (d - 2));
        int lvl = base + 2 * q;
        int n = qsel(q, ns.n[base], ns.n[base + 2], ns.n[base + 4], ns.n[base + 6]);
        fn_[d] = (float)n;
        np1_[d] = n + 1;
        np1sq_[d] = (n + 1) * (n + 1);
        dense_[d] = (ns.densemask >> lvl) & 1u;
        eb_[d] = embed + (size_t)lvl * (TSIZE * 2);
    }

    for (int tile = waveId; tile < numTiles; tile += waveStride) {
        const int ptg = tile * 16 + pt;
        const float* xp = x + (size_t)ptg * 6;
        f32x2 x01 = *(const f32x2*)(xp);
        f32x2 x23 = *(const f32x2*)(xp + 2);
        f32x2 x45 = *(const f32x2*)(xp + 4);
        float vx = x23.y, vy = x45.x, vz = x45.y;

        f32x2 fe[4][8];
        float w_[4][3];
        enc_issue(x01.x, x01.y, x23.x, fn_, eb_, np1_, np1sq_, dense_, fe, w_);

        Frag bf0, bf1;
        #pragma unroll
        for (int d = 0; d < 4; ++d) {
            float w0 = w_[d][0], w1 = w_[d][1], w2 = w_[d][2];
            float u0 = 1.0f - w0, u1 = 1.0f - w1, u2 = 1.0f - w2;
            float wxy[4] = { u0 * u1, u0 * w1, w0 * u1, w0 * w1 };
            float a0 = 0.0f, a1 = 0.0f;
            #pragma unroll
            for (int c = 0; c < 8; ++c) {
                float ww = wxy[c >> 1] * ((c & 1) ? w2 : u2);
                a0 = fmaf(fe[d][c].x, ww, a0);
                a1 = fmaf(fe[d][c].y, ww, a1);
            }
            if (d == 0)      { bf0.v[0] = (_Float16)a0; bf0.v[1] = (_Float16)a1; }
            else if (d == 1) { bf0.v[2] = (_Float16)a0; bf0.v[3] = (_Float16)a1; }
            else if (d == 2) { bf1.v[0] = (_Float16)a0; bf1.v[1] = (_Float16)a1; }
            else             { bf1.v[2] = (_Float16)a0; bf1.v[3] = (_Float16)a1; }
        }

        const float* db0o = db0; const float* db1o = db1;
        const float* cb0o = cb0; const float* cb1o = cb1;
        const float* cb2o = cb2;
        opaque(db0o); opaque(db1o); opaque(cb0o); opaque(cb1o); opaque(cb2o);

        f32x4 acc[4];
        #pragma unroll
        for (int t = 0; t < 4; ++t) {
            acc[t] = *(const f32x4*)(db0o + 16 * t + 4 * q);
            acc[t] = mfma16(wdW0[t][0], bf0, acc[t]);
            acc[t] = mfma16(wdW0[t][1], bf1, acc[t]);
        }
        Frag bh[4];
        #pragma unroll
        for (int c = 0; c < 4; ++c) bh[c] = actpack(acc[c]);

        f32x4 h = *(const f32x4*)(db1o + 4 * q);
        #pragma unroll
        for (int c = 0; c < 4; ++c) h = mfma16(wdW1[c], bh[c], h);

        float dens = sigmoidf(h[0]);
        Frag bcin0, bcin1;
        {
            float a0v = (q == 0) ? dens : fmaxf(h[0], 0.0f);
            bcin0.v[0] = (_Float16)a0v;
            bcin0.v[1] = (_Float16)fmaxf(h[1], 0.0f);
            bcin0.v[2] = (_Float16)fmaxf(h[2], 0.0f);
            bcin0.v[3] = (_Float16)fmaxf(h[3], 0.0f);
            bcin1.v[0] = (_Float16)((q == 0) ? vx : 0.0f);
            bcin1.v[1] = (_Float16)((q == 0) ? vy : 0.0f);
            bcin1.v[2] = (_Float16)((q == 0) ? vz : 0.0f);
            bcin1.v[3] = (_Float16)0.0f;
        }

        #pragma unroll
        for (int t = 0; t < 4; ++t) {
            acc[t] = *(const f32x4*)(cb0o + 16 * t + 4 * q);
            acc[t] = mfma16(wcW0[t][0], bcin0, acc[t]);
            acc[t] = mfma16(wcW0[t][1], bcin1, acc[t]);
        }
        Frag bc[4];
        #pragma unroll
        for (int c = 0; c < 4; ++c) bc[c] = actpack(acc[c]);

        #pragma unroll
        for (int t = 0; t < 4; ++t) {
            acc[t] = *(const f32x4*)(cb1o + 16 * t + 4 * q);
            #pragma unroll
            for (int c = 0; c < 4; ++c) acc[t] = mfma16(wcW1[t][c], bc[c], acc[t]);
        }
        Frag bd[4];
        #pragma unroll
        for (int c = 0; c < 4; ++c) bd[c] = actpack(acc[c]);

        float b0 = cb2o[0], b1 = cb2o[1], b2 = cb2o[2];
        f32x4 fo;
        fo[0] = (q == 0) ? b0 : 0.0f;
        fo[1] = (q == 0) ? b1 : 0.0f;
        fo[2] = (q == 0) ? b2 : 0.0f;
        fo[3] = 0.0f;
        #pragma unroll
        for (int c = 0; c < 4; ++c) fo = mfma16(wcW2[c], bd[c], fo);

        if (q == 0) {
            f32x4 o;
            o[0] = dens;
            o[1] = sigmoidf(fo[0]);
            o[2] = sigmoidf(fo[1]);
            o[3] = sigmoidf(fo[2]);
            *(f32x4*)(out + (size_t)ptg * 4) = o;
        }
    }
}

extern "C" void kernel_launch(void* const* d_in, const int* in_sizes, int n_in,
                              void* d_out, int out_size, void* d_ws, size_t ws_size,
                              hipStream_t stream) {
    const float* x    = (const float*)d_in[0];
    const float* embed= (const float*)d_in[1];
    const float* dW0  = (const float*)d_in[2];
    const float* db0  = (const float*)d_in[3];
    const float* dW1  = (const float*)d_in[4];
    const float* db1  = (const float*)d_in[5];
    const float* cW0  = (const float*)d_in[6];
    const float* cb0  = (const float*)d_in[7];
    const float* cW1  = (const float*)d_in[8];
    const float* cb1  = (const float*)d_in[9];
    const float* cW2  = (const float*)d_in[10];
    const float* cb2  = (const float*)d_in[11];
    float* out = (float*)d_out;

    int B = in_sizes[0] / 6;

    // Replicate numpy's NS computation bit-for-bit (same libm on this host).
    NsParam ns;
    double g = exp((log(512.0) - log(16.0)) / 15.0);
    ns.densemask = 0;
    for (int i = 0; i < NLEVEL; ++i) {
        ns.n[i] = (int)(16.0 * pow(g, (double)i));
        long long np1 = ns.n[i] + 1;
        if (np1 * np1 * np1 <= TSIZE) ns.densemask |= (1u << i);
    }

    size_t wsMain = (size_t)NLEVEL * (size_t)B * 4;  // fp16x2 per (level,point)
    size_t wsQ    = (size_t)B * 8;                   // u16x3 qcoords, 8B/pt
    bool okMain = ws_size >= wsMain && d_ws != nullptr &&
                  (B & 31) == 0 && B >= 32;
    if (okMain && ws_size >= wsMain + wsQ) {
        unsigned* ws = (unsigned*)d_ws;
        u32x2* qcv = (u32x2*)(ws + (size_t)NLEVEL * B);
        nerf_prep<<<2048, 256, 0, stream>>>(x, qcv, B);
        nerf_encode<true><<<1024, 1024, 0, stream>>>(
            x, (const unsigned*)qcv, embed, ws, B, ns);
        nerf_mlp<<<2048, 256, 0, stream>>>(x, ws,
            dW0, db0, dW1, db1, cW0, cb0, cW1, cb1, cW2, cb2, out, B);
    } else if (okMain) {
        unsigned* ws = (unsigned*)d_ws;
        nerf_encode<false><<<1024, 1024, 0, stream>>>(
            x, nullptr, embed, ws, B, ns);
        nerf_mlp<<<2048, 256, 0, stream>>>(x, ws,
            dW0, db0, dW1, db1, cW0, cb0, cW1, cb1, cW2, cb2, out, B);
    } else {
        nerf_fused<<<2048, 256, 0, stream>>>(x, embed,
            dW0, db0, dW1, db1, cW0, cb0, cW1, cb1, cW2, cb2, out, B, ns);
    }
}

// Round 10
// 248.577 us; speedup vs baseline: 1.1600x; 1.0256x over previous
//
#include <hip/hip_runtime.h>
#include <math.h>

#define NLEVEL 16
#define TSIZE 16384
#define ESTRIDE 65536   // encode: 64 slices x 1024 threads

using half4 = __attribute__((ext_vector_type(4))) _Float16;
using f32x4 = __attribute__((ext_vector_type(4))) float;
using f32x2 = __attribute__((ext_vector_type(2))) float;
using u32x2 = __attribute__((ext_vector_type(2))) unsigned;
typedef __fp16 hv2 __attribute__((ext_vector_type(2)));

struct NsParam { int n[NLEVEL]; unsigned densemask; };

union Frag { half4 v; int i[2]; };
union Hu { unsigned u; hv2 h; };

// A-fragment for mfma_f32_16x16x16f16 of W^T (W row-major [K][N] fp32):
// lane (pt=lane&15, q=lane>>4) holds A[m=out][k=k0+4q+j], j=0..3.
__device__ __forceinline__ Frag load_wfrag(const float* __restrict__ W, int ldn,
                                           int k0, int q, int out,
                                           int kmax, int omax) {
    Frag f;
    #pragma unroll
    for (int j = 0; j < 4; ++j) {
        int k = k0 + 4 * q + j;
        float v = (k < kmax && out < omax) ? W[k * ldn + out] : 0.0f;
        f.v[j] = (_Float16)v;
    }
    return f;
}

__device__ __forceinline__ f32x4 mfma16(const Frag& a, const Frag& b, f32x4 c) {
    return __builtin_amdgcn_mfma_f32_16x16x16f16(a.v, b.v, c, 0, 0, 0);
}

// relu + cvt: C-tile f32x4 -> B-fragment half4 (layouts match for K=16!)
__device__ __forceinline__ Frag actpack(f32x4 a) {
    Frag f;
    #pragma unroll
    for (int j = 0; j < 4; ++j) f.v[j] = (_Float16)fmaxf(a[j], 0.0f);
    return f;
}

// exact-path sigmoid (fallback/fused kernels keep bit-compat with r0-r9)
__device__ __forceinline__ float sigmoidf(float x) {
    return 1.0f / (1.0f + expf(-x));
}

// fast sigmoid for the mlp epilogue: native v_exp + v_rcp.
// abs err ~1e-7 << fp16 output quantum (2^-11) << absmax budget 0.0039.
__device__ __forceinline__ float sigmoid_fast(float x) {
    float e = __expf(-x);
    return __builtin_amdgcn_rcpf(1.0f + e);
}

// q-select among 4 values (q = lane>>4)
__device__ __forceinline__ int qsel(int q, int a, int b, int c, int d) {
    return (q & 2) ? ((q & 1) ? d : c) : ((q & 1) ? b : a);
}

// packed f32x2 -> fp16x2 (RTZ; staging the LDS table copy)
__device__ __forceinline__ unsigned pkrtz(float a, float b) {
    union { hv2 h; unsigned u; } r;
    r.h = __builtin_amdgcn_cvt_pkrtz(a, b);
    return r.u;
}

// RTN scalar-cast pack (matches the rounding the mlp used in-place before)
__device__ __forceinline__ unsigned pkrtn(float a, float b) {
    union { _Float16 h[2]; unsigned u; } r;
    r.h[0] = (_Float16)a; r.h[1] = (_Float16)b;
    return r.u;
}

__device__ __forceinline__ hv2 splath(float w) {
    Hu r; r.u = pkrtz(w, w); return r.h;
}

// packed-fp16 lerp: a + w*(b-a)
__device__ __forceinline__ hv2 hlerp(hv2 a, hv2 b, hv2 w) {
    return (hv2)((b - a) * w + a);
}

// ============================================================================
// Phase 0: coord prep. Reads x ONCE. Round-10 delta: besides the u16x3
// qcoords (8B/pt), also writes a packed-fp16 VIEW-DIR plane (8B/pt, RTN
// casts identical to what the mlp previously did in-place). The mlp then
// touches NO strided x memory at all (r9 mlp FETCH 90MB, features only 32).
// ============================================================================
__global__ __launch_bounds__(256) void nerf_prep(
    const float* __restrict__ x, u32x2* __restrict__ qc,
    u32x2* __restrict__ vd, int B)
{
    int i = blockIdx.x * blockDim.x + threadIdx.x;
    const int stride = gridDim.x * blockDim.x;
    for (; i < B; i += stride) {
        const float* xp = x + (size_t)i * 6;
        f32x2 a01 = *(const f32x2*)xp;
        f32x2 a23 = *(const f32x2*)(xp + 2);
        f32x2 a45 = *(const f32x2*)(xp + 4);
        float cx = fminf(fmaxf((a01.x + 5.0f) / 10.0f, 0.0f), 0.999999f);
        float cy = fminf(fmaxf((a01.y + 5.0f) / 10.0f, 0.0f), 0.999999f);
        float cz = fminf(fmaxf((a23.x + 5.0f) / 10.0f, 0.0f), 0.999999f);
        unsigned qx = (unsigned)(cx * 65536.0f);   // <= 65535
        unsigned qy = (unsigned)(cy * 65536.0f);
        unsigned qz = (unsigned)(cz * 65536.0f);
        u32x2 o; o.x = qx | (qy << 16); o.y = qz;
        qc[i] = o;
        u32x2 v; v.x = pkrtn(a23.y, a45.x); v.y = pkrtn(a45.y, 0.0f);
        vd[i] = v;
    }
}

// ============================================================================
// Phase A: hash-grid encode, level-persistent blocks (unchanged from r9:
// fp16 table staged once per block, byte-offset Gray-code hash, 1024 blocks
// for refill, nt feature stores, qcoord input).
// ============================================================================

__device__ __forceinline__ void gather_issue(
    const unsigned* __restrict__ tab,
    float cxp, float cyp, float czp,
    float scale, int np1b, int np1sqb, int dense,
    unsigned fe[8], float& w0, float& w1, float& w2)
{
    float xl0 = cxp * scale, xl1 = cyp * scale, xl2 = czp * scale;
    float f0 = floorf(xl0), f1 = floorf(xl1), f2 = floorf(xl2);
    int i0 = (int)f0, i1 = (int)f1, i2 = (int)f2;
    w0 = xl0 - f0; w1 = xl1 - f1; w2 = xl2 - f2;
    const char* tb = (const char*)tab;
    if (dense) {   // block-uniform branch (levels 0,1 only)
        int b000 = i0 * np1sqb + i1 * np1b + (i2 << 2);
        #pragma unroll
        for (int c = 0; c < 8; ++c) {
            int o0 = (c >> 2) & 1, o1 = (c >> 1) & 1, o2 = c & 1;
            int off = b000 + (o0 ? np1sqb : 0) + (o1 ? np1b : 0) + (o2 << 2);
            fe[c] = *(const unsigned*)(tb + off);
        }
    } else {
        unsigned HX = (unsigned)i0 << 2;
        unsigned HY = (unsigned)i1 * (2654435761u << 2);
        unsigned HZ = (unsigned)i2 * (805459861u << 2);
        unsigned A  = HX ^ HY ^ HZ;
        unsigned DX = HX ^ (HX + 4u);
        unsigned DY = HY ^ (HY + (2654435761u << 2));
        unsigned DZ = HZ ^ (HZ + (805459861u << 2));
        const unsigned mask = (TSIZE - 1) << 2;
        unsigned b00 = A,        b10 = A ^ DX;
        unsigned b01 = b00 ^ DY, b11 = b10 ^ DY;
        fe[0] = *(const unsigned*)(tb + (b00 & mask));
        fe[1] = *(const unsigned*)(tb + ((b00 ^ DZ) & mask));
        fe[2] = *(const unsigned*)(tb + (b01 & mask));
        fe[3] = *(const unsigned*)(tb + ((b01 ^ DZ) & mask));
        fe[4] = *(const unsigned*)(tb + (b10 & mask));
        fe[5] = *(const unsigned*)(tb + ((b10 ^ DZ) & mask));
        fe[6] = *(const unsigned*)(tb + (b11 & mask));
        fe[7] = *(const unsigned*)(tb + ((b11 ^ DZ) & mask));
    }
}

__device__ __forceinline__ unsigned interp_tree(
    const unsigned fe[8], float w0, float w1, float w2)
{
    hv2 W0 = splath(w0), W1 = splath(w1), W2 = splath(w2);
    Hu a, b;
    a.u = fe[0]; b.u = fe[1]; hv2 g00 = hlerp(a.h, b.h, W2);
    a.u = fe[2]; b.u = fe[3]; hv2 g01 = hlerp(a.h, b.h, W2);
    a.u = fe[4]; b.u = fe[5]; hv2 g10 = hlerp(a.h, b.h, W2);
    a.u = fe[6]; b.u = fe[7]; hv2 g11 = hlerp(a.h, b.h, W2);
    hv2 gy0 = hlerp(g00, g01, W1);
    hv2 gy1 = hlerp(g10, g11, W1);
    Hu r; r.h = hlerp(gy0, gy1, W0);
    return r.u;
}

// load 4 chunk coords (indices clamped so overrun prefetch is safe)
template <bool QC>
__device__ __forceinline__ void loadc4(
    const float* __restrict__ x, const unsigned* __restrict__ qc,
    int g0, int chunk, int B, float cx[4], float cy[4], float cz[4])
{
    #pragma unroll
    for (int p = 0; p < 4; ++p) {
        int idx = g0 + (chunk * 4 + p) * ESTRIDE;
        idx = (idx < B) ? idx : (B - 1);
        if (QC) {
            u32x2 qq = *((const u32x2*)qc + idx);
            cx[p] = (float)(qq.x & 0xFFFFu);
            cy[p] = (float)(qq.x >> 16);
            cz[p] = (float)qq.y;
        } else {
            const float* xp = x + (size_t)idx * 6;
            f32x2 a = *(const f32x2*)xp;
            float pz = xp[2];
            cx[p] = fminf(fmaxf((a.x + 5.0f) / 10.0f, 0.0f), 0.999999f);
            cy[p] = fminf(fmaxf((a.y + 5.0f) / 10.0f, 0.0f), 0.999999f);
            cz[p] = fminf(fmaxf((pz  + 5.0f) / 10.0f, 0.0f), 0.999999f);
        }
    }
}

__device__ __forceinline__ void enc_chunk(
    const unsigned* __restrict__ tab, unsigned* __restrict__ wplane,
    int g0, int chunk, int B,
    const float cx[4], const float cy[4], const float cz[4],
    float scale, int np1b, int np1sqb, int dense)
{
    unsigned fe[2][8];
    float w0s[2], w1s[2], w2s[2];
    gather_issue(tab, cx[0], cy[0], cz[0], scale, np1b, np1sqb, dense,
                 fe[0], w0s[0], w1s[0], w2s[0]);
    #pragma unroll
    for (int p = 0; p < 4; ++p) {
        if (p + 1 < 4)
            gather_issue(tab, cx[p + 1], cy[p + 1], cz[p + 1],
                         scale, np1b, np1sqb, dense,
                         fe[(p + 1) & 1], w0s[(p + 1) & 1],
                         w1s[(p + 1) & 1], w2s[(p + 1) & 1]);
        unsigned pk = interp_tree(fe[p & 1], w0s[p & 1], w1s[p & 1], w2s[p & 1]);
        int idx = g0 + (chunk * 4 + p) * ESTRIDE;
        if (idx < B) __builtin_nontemporal_store(pk, wplane + idx);
    }
}

template <bool QC>
__global__ __launch_bounds__(1024, 8) void nerf_encode(
    const float* __restrict__ x, const unsigned* __restrict__ qc,
    const float* __restrict__ embed,
    unsigned* __restrict__ ws, int B, NsParam ns)
{
    __shared__ unsigned tab[TSIZE];   // fp16x2 entries, 64 KB -> 2 blocks/CU
    const int tid = threadIdx.x;
    const int l = blockIdx.x & 15;        // level (interleaved for refill mix)
    const int slice = blockIdx.x >> 4;    // 0..63

    // stage this level's fp16 table ONCE
    {
        const f32x4* src = (const f32x4*)(embed + (size_t)l * (TSIZE * 2));
        #pragma unroll
        for (int j = 0; j < 8; ++j) {
            f32x4 v = src[tid + 1024 * j];
            u32x2 pk;
            pk.x = pkrtz(v.x, v.y);
            pk.y = pkrtz(v.z, v.w);
            *(u32x2*)(tab + 2 * (tid + 1024 * j)) = pk;
        }
    }
    __syncthreads();

    const int n = ns.n[l];
    const float scale = QC ? (float)n * (1.0f / 65536.0f) : (float)n;
    const int np1b = (n + 1) << 2, np1sqb = (n + 1) * (n + 1) << 2;
    const int dense = (ns.densemask >> l) & 1;
    unsigned* __restrict__ wplane = ws + (size_t)l * B;

    const int g0 = slice * 1024 + tid;    // 0..65535
    const int nIter = (B + ESTRIDE - 1) / ESTRIDE;   // points per thread (32)
    const int NC = (nIter + 3) >> 2;                 // 4-pt chunks (8)

    float cxA[4], cyA[4], czA[4], cxB[4], cyB[4], czB[4];
    loadc4<QC>(x, qc, g0, 0, B, cxA, cyA, czA);
    for (int c = 0; c < NC; c += 2) {
        loadc4<QC>(x, qc, g0, c + 1, B, cxB, cyB, czB);
        enc_chunk(tab, wplane, g0, c, B, cxA, cyA, czA,
                  scale, np1b, np1sqb, dense);
        loadc4<QC>(x, qc, g0, c + 2, B, cxA, cyA, czA);
        if (c + 1 < NC)
            enc_chunk(tab, wplane, g0, c + 1, B, cxB, cyB, czB,
                      scale, np1b, np1sqb, dense);
    }
}

// ============================================================================
// Phase B: MFMA MLP, 32 points per wave-iteration (two independent chains).
// Round-10 deltas (r9 counters: VALUBusy 70%, MfmaUtil 34% -> VALU-bound):
// (1) template<VD>: view dirs from prep's packed-fp16 plane -- no strided x
//     loads (r9 FETCH 90MB vs 32MB features) and bcin1 built with 4 integer
//     cndmasks instead of 6 cvt + 6 selects;
// (2) sigmoid_fast (native v_exp + v_rcp) for the 8 sigmoids/iter.
// ============================================================================
struct Pre { Frag f0[2], f1[2]; int vd0[2], vd1[2]; };

template <bool VD>
__device__ __forceinline__ void prefetch_tile(
    const unsigned* __restrict__ ws, const u32x2* __restrict__ vd, int B, int q,
    const float* __restrict__ x, int tile32, int pt, Pre& P)
{
    const unsigned* pl0 = ws + (size_t)(2 * q) * B;
    const unsigned* pl1 = ws + (size_t)(2 * q + 1) * B;
    const unsigned* pl2 = ws + (size_t)(8 + 2 * q) * B;
    const unsigned* pl3 = ws + (size_t)(9 + 2 * q) * B;
    #pragma unroll
    for (int g = 0; g < 2; ++g) {
        int ptg = tile32 * 32 + g * 16 + pt;
        P.f0[g].i[0] = (int)__builtin_nontemporal_load(pl0 + ptg);
        P.f0[g].i[1] = (int)__builtin_nontemporal_load(pl1 + ptg);
        P.f1[g].i[0] = (int)__builtin_nontemporal_load(pl2 + ptg);
        P.f1[g].i[1] = (int)__builtin_nontemporal_load(pl3 + ptg);
        if (VD) {
            u32x2 v = __builtin_nontemporal_load(vd + ptg);
            P.vd0[g] = (int)v.x; P.vd1[g] = (int)v.y;
        } else {
            const float* xp = x + (size_t)ptg * 6;
            float vx = xp[3];
            f32x2 v45 = *(const f32x2*)(xp + 4);
            P.vd0[g] = (int)pkrtn(vx, v45.x);
            P.vd1[g] = (int)pkrtn(v45.y, 0.0f);
        }
    }
}

template <bool VD>
__global__ __launch_bounds__(256, 4) void nerf_mlp(
    const float* __restrict__ x,
    const unsigned* __restrict__ ws, const u32x2* __restrict__ vd,
    const float* __restrict__ dW0, const float* __restrict__ db0,
    const float* __restrict__ dW1, const float* __restrict__ db1,
    const float* __restrict__ cW0, const float* __restrict__ cb0,
    const float* __restrict__ cW1, const float* __restrict__ cb1,
    const float* __restrict__ cW2, const float* __restrict__ cb2,
    float* __restrict__ out, int B)
{
    const int lane = threadIdx.x & 63;
    const int pt = lane & 15;
    const int q  = lane >> 4;
    const int tid = threadIdx.x;
    const int wavesPerBlock = blockDim.x >> 6;
    const int waveId = blockIdx.x * wavesPerBlock + (threadIdx.x >> 6);
    const int waveStride = gridDim.x * wavesPerBlock;
    const int numT = B >> 5;   // 32-pt tiles

    // LDS-resident: cW0 (8 frags x 64 lanes), cW1 (16 x 64), biases
    __shared__ Frag wldsC0[8][64];    // 4 KB
    __shared__ Frag wldsC1[16][64];   // 8 KB
    __shared__ f32x4 blds[14][4];     // 896 B
    for (int e = tid; e < 8 * 64; e += 256) {
        int f = e >> 6, ln = e & 63;
        wldsC0[f][ln] = load_wfrag(cW0, 64, 16 * (f & 1), ln >> 4,
                                   16 * (f >> 1) + (ln & 15), 19, 64);
    }
    for (int e = tid; e < 16 * 64; e += 256) {
        int f = e >> 6, ln = e & 63;
        wldsC1[f][ln] = load_wfrag(cW1, 64, 16 * (f & 3), ln >> 4,
                                   16 * (f >> 2) + (ln & 15), 64, 64);
    }
    if (tid < 56) {
        int f = tid >> 2, qq = tid & 3;
        f32x4 v;
        if (f < 4)       v = *(const f32x4*)(db0 + 16 * f + 4 * qq);
        else if (f == 4) v = *(const f32x4*)(db1 + 4 * qq);
        else if (f < 9)  v = *(const f32x4*)(cb0 + 16 * (f - 5) + 4 * qq);
        else if (f < 13) v = *(const f32x4*)(cb1 + 16 * (f - 9) + 4 * qq);
        else {
            v[0] = (qq == 0) ? cb2[0] : 0.0f;
            v[1] = (qq == 0) ? cb2[1] : 0.0f;
            v[2] = (qq == 0) ? cb2[2] : 0.0f;
            v[3] = 0.0f;
        }
        blds[f][qq] = v;
    }

    // VGPR-resident weights: dW0 (8), dW1 (4), cW2 (4) frags = 32 VGPRs
    Frag wdW0[4][2], wdW1[4], wcW2[4];
    #pragma unroll
    for (int t = 0; t < 4; ++t)
        #pragma unroll
        for (int c = 0; c < 2; ++c)
            wdW0[t][c] = load_wfrag(dW0, 64, 16 * c, q, 16 * t + pt, 32, 64);
    #pragma unroll
    for (int c = 0; c < 4; ++c)
        wdW1[c] = load_wfrag(dW1, 16, 16 * c, q, pt, 64, 16);
    #pragma unroll
    for (int c = 0; c < 4; ++c)
        wcW2[c] = load_wfrag(cW2, 3, 16 * c, q, pt, 64, 3);

    __syncthreads();

    int tile = waveId;
    if (tile >= numT) return;

    Pre P;
    prefetch_tile<VD>(ws, vd, B, q, x, tile, pt, P);

    for (;;) {
        int next = tile + waveStride;
        bool hasNext = next < numT;

        // consume prefetched registers (waits on loads issued 1 iter ago)
        Frag bf0[2] = { P.f0[0], P.f0[1] };
        Frag bf1[2] = { P.f1[0], P.f1[1] };
        int vd0[2] = { P.vd0[0], P.vd0[1] };
        int vd1[2] = { P.vd1[0], P.vd1[1] };
        const int ptbase = tile * 32;

        if (hasNext) prefetch_tile<VD>(ws, vd, B, q, x, next, pt, P);

        // fresh opaque indices each iteration: stops LICM hoisting the
        // loop-invariant LDS reads back into permanently-live VGPRs.
        int wl = lane, wq = q;
        asm("" : "+v"(wl));
        asm("" : "+v"(wq));

        __builtin_amdgcn_s_setprio(1);

        // ---- L0: h64 = dW0^T @ feats (4 out-tiles, K=32) x 2 chains ----
        f32x4 acc[2][4];
        #pragma unroll
        for (int t = 0; t < 4; ++t) {
            f32x4 b = blds[t][wq];
            #pragma unroll
            for (int g = 0; g < 2; ++g) {
                f32x4 a = b;
                a = mfma16(wdW0[t][0], bf0[g], a);
                a = mfma16(wdW0[t][1], bf1[g], a);
                acc[g][t] = a;
            }
        }
        Frag bh[2][4];
        #pragma unroll
        for (int c = 0; c < 4; ++c)
            #pragma unroll
            for (int g = 0; g < 2; ++g) bh[g][c] = actpack(acc[g][c]);

        // ---- L1: h16 = dW1^T @ relu(h64) (1 tile, K=64) ----
        f32x4 bl1 = blds[4][wq];
        f32x4 h[2] = { bl1, bl1 };
        #pragma unroll
        for (int c = 0; c < 4; ++c)
            #pragma unroll
            for (int g = 0; g < 2; ++g) h[g] = mfma16(wdW1[c], bh[g][c], h[g]);

        float dens[2];
        Frag bcin0[2], bcin1[2];
        #pragma unroll
        for (int g = 0; g < 2; ++g) {
            dens[g] = sigmoid_fast(h[g][0]);    // row 0 lives at q==0, reg 0
            float a0v = (q == 0) ? dens[g] : fmaxf(h[g][0], 0.0f);
            bcin0[g].v[0] = (_Float16)a0v;
            bcin0[g].v[1] = (_Float16)fmaxf(h[g][1], 0.0f);
            bcin0[g].v[2] = (_Float16)fmaxf(h[g][2], 0.0f);
            bcin0[g].v[3] = (_Float16)fmaxf(h[g][3], 0.0f);
            // k=16+4q+j: q==0 holds k16..19 = (vx,vy,vz,0) of its own point
            // (prepacked fp16 bits; integer select, no cvt)
            bcin1[g].i[0] = (q == 0) ? vd0[g] : 0;
            bcin1[g].i[1] = (q == 0) ? vd1[g] : 0;
        }

        // ---- L2: c1 = cW0^T @ cin (4 out-tiles, K=19 padded to 32) ----
        #pragma unroll
        for (int t = 0; t < 4; ++t) {
            f32x4 b = blds[5 + t][wq];
            Frag w0f = wldsC0[2 * t + 0][wl];
            Frag w1f = wldsC0[2 * t + 1][wl];
            #pragma unroll
            for (int g = 0; g < 2; ++g) {
                f32x4 a = b;
                a = mfma16(w0f, bcin0[g], a);
                a = mfma16(w1f, bcin1[g], a);
                acc[g][t] = a;
            }
        }
        Frag bc[2][4];
        #pragma unroll
        for (int c = 0; c < 4; ++c)
            #pragma unroll
            for (int g = 0; g < 2; ++g) bc[g][c] = actpack(acc[g][c]);

        // ---- L3: c2 = cW1^T @ relu(c1) (4 out-tiles, K=64) ----
        #pragma unroll
        for (int t = 0; t < 4; ++t) {
            f32x4 b = blds[9 + t][wq];
            #pragma unroll
            for (int g = 0; g < 2; ++g) acc[g][t] = b;
            #pragma unroll
            for (int c = 0; c < 4; ++c) {
                Frag wf = wldsC1[4 * t + c][wl];
                #pragma unroll
                for (int g = 0; g < 2; ++g)
                    acc[g][t] = mfma16(wf, bc[g][c], acc[g][t]);
            }
        }
        Frag bd[2][4];
        #pragma unroll
        for (int c = 0; c < 4; ++c)
            #pragma unroll
            for (int g = 0; g < 2; ++g) bd[g][c] = actpack(acc[g][c]);

        // ---- L4: col = cW2^T @ relu(c2) (rows 0..2, K=64) ----
        f32x4 bl4 = blds[13][wq];
        f32x4 fo[2] = { bl4, bl4 };
        #pragma unroll
        for (int c = 0; c < 4; ++c)
            #pragma unroll
            for (int g = 0; g < 2; ++g) fo[g] = mfma16(wcW2[c], bd[g][c], fo[g]);

        __builtin_amdgcn_s_setprio(0);

        if (q == 0) {
            #pragma unroll
            for (int g = 0; g < 2; ++g) {
                f32x4 o;
                o[0] = dens[g];
                o[1] = sigmoid_fast(fo[g][0]);
                o[2] = sigmoid_fast(fo[g][1]);
                o[3] = sigmoid_fast(fo[g][2]);
                __builtin_nontemporal_store(o,
                    (f32x4*)(out + (size_t)(ptbase + g * 16 + pt) * 4));
            }
        }

        if (!hasNext) break;
        tile = next;
    }
}

// ============================================================================
// Fallback: fused single kernel if ws_size is insufficient (unchanged).
// ============================================================================
__device__ __forceinline__ void opaque(const float*& p) {
    asm("" : "+v"(p));
}

__device__ __forceinline__ void enc_issue(
    float px, float py, float pz,
    const float fn_[4], const float* const eb_[4],
    const int np1_[4], const int np1sq_[4], const bool dense_[4],
    f32x2 fe[4][8], float w_[4][3])
{
    float cx = fminf(fmaxf((px + 5.0f) / 10.0f, 0.0f), 0.999999f);
    float cy = fminf(fmaxf((py + 5.0f) / 10.0f, 0.0f), 0.999999f);
    float cz = fminf(fmaxf((pz + 5.0f) / 10.0f, 0.0f), 0.999999f);

    #pragma unroll
    for (int d = 0; d < 4; ++d) {
        float fn = fn_[d];
        float xl0 = cx * fn, xl1 = cy * fn, xl2 = cz * fn;
        float f0 = floorf(xl0), f1 = floorf(xl1), f2 = floorf(xl2);
        int i0 = (int)f0, i1 = (int)f1, i2 = (int)f2;
        w_[d][0] = xl0 - f0; w_[d][1] = xl1 - f1; w_[d][2] = xl2 - f2;

        unsigned hx0 = (unsigned)i0, hx1 = hx0 + 1u;
        unsigned hy0 = (unsigned)i1 * 2654435761u, hy1 = hy0 + 2654435761u;
        unsigned hz0 = (unsigned)i2 * 805459861u,  hz1 = hz0 + 805459861u;
        int dx0 = 0, dx1 = 0, dy0 = 0, dy1 = 0;
        if (d < 2) {
            dx0 = i0 * np1sq_[d]; dx1 = dx0 + np1sq_[d];
            dy0 = i1 * np1_[d];   dy1 = dy0 + np1_[d];
        }
        #pragma unroll
        for (int c = 0; c < 8; ++c) {
            int o0 = (c >> 2) & 1, o1 = (c >> 1) & 1, o2 = c & 1;
            unsigned h = (o0 ? hx1 : hx0) ^ (o1 ? hy1 : hy0) ^ (o2 ? hz1 : hz0);
            int ind = (int)(h & (TSIZE - 1));
            if (d < 2) {
                int di = (o0 ? dx1 : dx0) + (o1 ? dy1 : dy0) + i2 + o2;
                ind = dense_[d] ? di : ind;
            }
            fe[d][c] = *(const f32x2*)(eb_[d] + (size_t)ind * 2);
        }
    }
}

__global__ __launch_bounds__(256) void nerf_fused(
    const float* __restrict__ x,
    const float* __restrict__ embed,
    const float* __restrict__ dW0, const float* __restrict__ db0,
    const float* __restrict__ dW1, const float* __restrict__ db1,
    const float* __restrict__ cW0, const float* __restrict__ cb0,
    const float* __restrict__ cW1, const float* __restrict__ cb1,
    const float* __restrict__ cW2, const float* __restrict__ cb2,
    float* __restrict__ out, int B, NsParam ns)
{
    const int lane = threadIdx.x & 63;
    const int pt = lane & 15;
    const int q  = lane >> 4;
    const int wavesPerBlock = blockDim.x >> 6;
    const int waveId = blockIdx.x * wavesPerBlock + (threadIdx.x >> 6);
    const int waveStride = gridDim.x * wavesPerBlock;
    const int numTiles = B >> 4;

    Frag wdW0[4][2], wdW1[4], wcW0[4][2], wcW1[4][4], wcW2[4];
    #pragma unroll
    for (int t = 0; t < 4; ++t)
        #pragma unroll
        for (int c = 0; c < 2; ++c)
            wdW0[t][c] = load_wfrag(dW0, 64, 16 * c, q, 16 * t + pt, 32, 64);
    #pragma unroll
    for (int c = 0; c < 4; ++c)
        wdW1[c] = load_wfrag(dW1, 16, 16 * c, q, pt, 64, 16);
    #pragma unroll
    for (int t = 0; t < 4; ++t)
        #pragma unroll
        for (int c = 0; c < 2; ++c)
            wcW0[t][c] = load_wfrag(cW0, 64, 16 * c, q, 16 * t + pt, 19, 64);
    #pragma unroll
    for (int t = 0; t < 4; ++t)
        #pragma unroll
        for (int c = 0; c < 4; ++c)
            wcW1[t][c] = load_wfrag(cW1, 64, 16 * c, q, 16 * t + pt, 64, 64);
    #pragma unroll
    for (int c = 0; c < 4; ++c)
        wcW2[c] = load_wfrag(cW2, 3, 16 * c, q, pt, 64, 3);

    float fn_[4];
    const float* eb_[4];
    int np1_[4], np1sq_[4];
    bool dense_[4];
    #pragma unroll
    for (int d = 0; d < 4; ++d) {
        int base = (d < 2) ? (d) : (8 + (d - 2));
        int lvl = base + 2 * q;
        int n = qsel(q, ns.n[base], ns.n[base + 2], ns.n[base + 4], ns.n[base + 6]);
        fn_[d] = (float)n;
        np1_[d] = n + 1;
        np1sq_[d] = (n + 1) * (n + 1);
        dense_[d] = (ns.densemask >> lvl) & 1u;
        eb_[d] = embed + (size_t)lvl * (TSIZE * 2);
    }

    for (int tile = waveId; tile < numTiles; tile += waveStride) {
        const int ptg = tile * 16 + pt;
        const float* xp = x + (size_t)ptg * 6;
        f32x2 x01 = *(const f32x2*)(xp);
        f32x2 x23 = *(const f32x2*)(xp + 2);
        f32x2 x45 = *(const f32x2*)(xp + 4);
        float vx = x23.y, vy = x45.x, vz = x45.y;

        f32x2 fe[4][8];
        float w_[4][3];
        enc_issue(x01.x, x01.y, x23.x, fn_, eb_, np1_, np1sq_, dense_, fe, w_);

        Frag bf0, bf1;
        #pragma unroll
        for (int d = 0; d < 4; ++d) {
            float w0 = w_[d][0], w1 = w_[d][1], w2 = w_[d][2];
            float u0 = 1.0f - w0, u1 = 1.0f - w1, u2 = 1.0f - w2;
            float wxy[4] = { u0 * u1, u0 * w1, w0 * u1, w0 * w1 };
            float a0 = 0.0f, a1 = 0.0f;
            #pragma unroll
            for (int c = 0; c < 8; ++c) {
                float ww = wxy[c >> 1] * ((c & 1) ? w2 : u2);
                a0 = fmaf(fe[d][c].x, ww, a0);
                a1 = fmaf(fe[d][c].y, ww, a1);
            }
            if (d == 0)      { bf0.v[0] = (_Float16)a0; bf0.v[1] = (_Float16)a1; }
            else if (d == 1) { bf0.v[2] = (_Float16)a0; bf0.v[3] = (_Float16)a1; }
            else if (d == 2) { bf1.v[0] = (_Float16)a0; bf1.v[1] = (_Float16)a1; }
            else             { bf1.v[2] = (_Float16)a0; bf1.v[3] = (_Float16)a1; }
        }

        const float* db0o = db0; const float* db1o = db1;
        const float* cb0o = cb0; const float* cb1o = cb1;
        const float* cb2o = cb2;
        opaque(db0o); opaque(db1o); opaque(cb0o); opaque(cb1o); opaque(cb2o);

        f32x4 acc[4];
        #pragma unroll
        for (int t = 0; t < 4; ++t) {
            acc[t] = *(const f32x4*)(db0o + 16 * t + 4 * q);
            acc[t] = mfma16(wdW0[t][0], bf0, acc[t]);
            acc[t] = mfma16(wdW0[t][1], bf1, acc[t]);
        }
        Frag bh[4];
        #pragma unroll
        for (int c = 0; c < 4; ++c) bh[c] = actpack(acc[c]);

        f32x4 h = *(const f32x4*)(db1o + 4 * q);
        #pragma unroll
        for (int c = 0; c < 4; ++c) h = mfma16(wdW1[c], bh[c], h);

        float dens = sigmoidf(h[0]);
        Frag bcin0, bcin1;
        {
            float a0v = (q == 0) ? dens : fmaxf(h[0], 0.0f);
            bcin0.v[0] = (_Float16)a0v;
            bcin0.v[1] = (_Float16)fmaxf(h[1], 0.0f);
            bcin0.v[2] = (_Float16)fmaxf(h[2], 0.0f);
            bcin0.v[3] = (_Float16)fmaxf(h[3], 0.0f);
            bcin1.v[0] = (_Float16)((q == 0) ? vx : 0.0f);
            bcin1.v[1] = (_Float16)((q == 0) ? vy : 0.0f);
            bcin1.v[2] = (_Float16)((q == 0) ? vz : 0.0f);
            bcin1.v[3] = (_Float16)0.0f;
        }

        #pragma unroll
        for (int t = 0; t < 4; ++t) {
            acc[t] = *(const f32x4*)(cb0o + 16 * t + 4 * q);
            acc[t] = mfma16(wcW0[t][0], bcin0, acc[t]);
            acc[t] = mfma16(wcW0[t][1], bcin1, acc[t]);
        }
        Frag bc[4];
        #pragma unroll
        for (int c = 0; c < 4; ++c) bc[c] = actpack(acc[c]);

        #pragma unroll
        for (int t = 0; t < 4; ++t) {
            acc[t] = *(const f32x4*)(cb1o + 16 * t + 4 * q);
            #pragma unroll
            for (int c = 0; c < 4; ++c) acc[t] = mfma16(wcW1[t][c], bc[c], acc[t]);
        }
        Frag bd[4];
        #pragma unroll
        for (int c = 0; c < 4; ++c) bd[c] = actpack(acc[c]);

        float b0 = cb2o[0], b1 = cb2o[1], b2 = cb2o[2];
        f32x4 fo;
        fo[0] = (q == 0) ? b0 : 0.0f;
        fo[1] = (q == 0) ? b1 : 0.0f;
        fo[2] = (q == 0) ? b2 : 0.0f;
        fo[3] = 0.0f;
        #pragma unroll
        for (int c = 0; c < 4; ++c) fo = mfma16(wcW2[c], bd[c], fo);

        if (q == 0) {
            f32x4 o;
            o[0] = dens;
            o[1] = sigmoidf(fo[0]);
            o[2] = sigmoidf(fo[1]);
            o[3] = sigmoidf(fo[2]);
            *(f32x4*)(out + (size_t)ptg * 4) = o;
        }
    }
}

extern "C" void kernel_launch(void* const* d_in, const int* in_sizes, int n_in,
                              void* d_out, int out_size, void* d_ws, size_t ws_size,
                              hipStream_t stream) {
    const float* x    = (const float*)d_in[0];
    const float* embed= (const float*)d_in[1];
    const float* dW0  = (const float*)d_in[2];
    const float* db0  = (const float*)d_in[3];
    const float* dW1  = (const float*)d_in[4];
    const float* db1  = (const float*)d_in[5];
    const float* cW0  = (const float*)d_in[6];
    const float* cb0  = (const float*)d_in[7];
    const float* cW1  = (const float*)d_in[8];
    const float* cb1  = (const float*)d_in[9];
    const float* cW2  = (const float*)d_in[10];
    const float* cb2  = (const float*)d_in[11];
    float* out = (float*)d_out;

    int B = in_sizes[0] / 6;

    // Replicate numpy's NS computation bit-for-bit (same libm on this host).
    NsParam ns;
    double g = exp((log(512.0) - log(16.0)) / 15.0);
    ns.densemask = 0;
    for (int i = 0; i < NLEVEL; ++i) {
        ns.n[i] = (int)(16.0 * pow(g, (double)i));
        long long np1 = ns.n[i] + 1;
        if (np1 * np1 * np1 <= TSIZE) ns.densemask |= (1u << i);
    }

    size_t wsMain = (size_t)NLEVEL * (size_t)B * 4;  // fp16x2 per (level,point)
    size_t wsQ    = (size_t)B * 8;                   // u16x3 qcoords, 8B/pt
    size_t wsV    = (size_t)B * 8;                   // fp16x3 view dirs, 8B/pt
    bool okMain = ws_size >= wsMain && d_ws != nullptr &&
                  (B & 31) == 0 && B >= 32;
    if (okMain && ws_size >= wsMain + wsQ + wsV) {
        unsigned* ws = (unsigned*)d_ws;
        u32x2* qcv = (u32x2*)(ws + (size_t)NLEVEL * B);
        u32x2* vdv = qcv + B;
        nerf_prep<<<2048, 256, 0, stream>>>(x, qcv, vdv, B);
        nerf_encode<true><<<1024, 1024, 0, stream>>>(
            x, (const unsigned*)qcv, embed, ws, B, ns);
        nerf_mlp<true><<<2048, 256, 0, stream>>>(x, ws, vdv,
            dW0, db0, dW1, db1, cW0, cb0, cW1, cb1, cW2, cb2, out, B);
    } else if (okMain) {
        unsigned* ws = (unsigned*)d_ws;
        nerf_encode<false><<<1024, 1024, 0, stream>>>(
            x, nullptr, embed, ws, B, ns);
        nerf_mlp<false><<<2048, 256, 0, stream>>>(x, ws, nullptr,
            dW0, db0, dW1, db1, cW0, cb0, cW1, cb1, cW2, cb2, out, B);
    } else {
        nerf_fused<<<2048, 256, 0, stream>>>(x, embed,
            dW0, db0, dW1, db1, cW0, cb0, cW1, cb1, cW2, cb2, out, B, ns);
    }
}